// Round 10
// baseline (232.688 us; speedup 1.0000x reference)
//
#include <hip/hip_runtime.h>
#include <cstdint>
#include <cstddef>

#define NN 50000
#define NE 800000
#define CAP 96      // max in-degree bucket (Poisson(16): P(deg>=96) ~ 1e-42)
#define NSEG 8      // dst-range segments (XCD-aligned via blockIdx&7)
#define SEGW 6250   // NN / NSEG

// ---------------- ws layout (units of 4 bytes) ----------------
constexpr size_t O_CNT   = 0;                        // int[NN]
constexpr size_t O_SLOT  = 50048;                    // ushort[NN*CAP] (region kept int-sized)
constexpr size_t O_NODAL = O_SLOT + (size_t)NN*CAP;  // float4[NN] {dinvc,dinv,el,er}
constexpr size_t O_VA    = O_NODAL + 200000;         // 64
constexpr size_t O_VB    = O_VA + 64;                // 64
constexpr size_t O_XB    = O_VB + 64;                // ushort[(NN+1)*64] bf16 x (+zero row)
constexpr size_t O_NSB   = O_XB + 1600032;           // ushort[NN*64] bf16 nsum
constexpr size_t O_T1B   = O_NSB + 1600000;          // ushort[(NN+1)*64] bf16 T1 (+zero row)
constexpr size_t O_V1B   = O_T1B + 1600032;          // ushort[NN*64]
constexpr size_t O_GB    = O_V1B + 1600000;          // ushort[NN*64]
constexpr size_t O_UB    = O_GB  + 1600000;          // ushort[NN*64]
constexpr size_t O_WPK   = O_UB  + 1600000;          // ushort[9*4096] bf16 weights
constexpr size_t O_CMB   = O_WPK + 18432;            // uint[NN*CAP] {s | bf16(dinvc)<<16}
// total ~78 MB

typedef __attribute__((ext_vector_type(8))) short short8;   // 8 bf16 (4 VGPRs)
typedef __attribute__((ext_vector_type(4))) float f32x4;

__device__ __forceinline__ float leaky02(float v){ return v >= 0.f ? v : 0.2f*v; }
__device__ __forceinline__ float eluf(float v){ return v > 0.f ? v : (__expf(v) - 1.f); }

// intra-wave LDS producer->consumer fence (wave-synchronous pattern)
__device__ __forceinline__ void lds_fence(){
  asm volatile("s_waitcnt lgkmcnt(0)" ::: "memory");
}

__device__ __forceinline__ unsigned short f2bf(float f){   // round-to-nearest-even
  unsigned u = __float_as_uint(f);
  unsigned r = (u + 0x7FFFu + ((u >> 16) & 1u)) >> 16;
  return (unsigned short)r;
}
__device__ __forceinline__ float bf2f(unsigned short b){
  return __uint_as_float(((unsigned)b) << 16);
}
__device__ __forceinline__ unsigned pack2(unsigned short lo, unsigned short hi){
  return (unsigned)lo | ((unsigned)hi << 16);
}

// ---------------- fused: XCD-segmented int4 bucket build + prep --------------------
// grid 6256: seg = b&7 commits only dst in [seg*6250,(seg+1)*6250) -> per-XCD slot
// region 1.2 MB stays L2-resident. Blocks 0..3135 additionally run prep work.
__global__ __launch_bounds__(256) void k_scatter(
    const int4* __restrict__ src4, const int4* __restrict__ dst4,
    int* __restrict__ cnt, unsigned short* __restrict__ slot,
    const float* __restrict__ W_mlp, const float* __restrict__ Wr,
    const float* __restrict__ W_cheb, const float* __restrict__ W_gin,
    const float* __restrict__ Wl, const float* __restrict__ W_gcn,
    const float* __restrict__ W_gat,
    const float* __restrict__ a_src, const float* __restrict__ a_dst,
    const float4* __restrict__ x4,
    float* __restrict__ va, float* __restrict__ vb,
    unsigned short* __restrict__ wpk,
    ushort4* __restrict__ xb4, ushort4* __restrict__ t1b4){
  int b = blockIdx.x;
  int seg = b & (NSEG-1);
  int i4 = (b >> 3)*256 + threadIdx.x;
  if (i4 < NE/4){
    int4 d = dst4[i4];
    int4 s = src4[i4];
    int pos;
    if (d.x / SEGW == seg){ pos = atomicAdd(&cnt[d.x], 1); if (pos < CAP) slot[(size_t)d.x*CAP + pos] = (unsigned short)s.x; }
    if (d.y / SEGW == seg){ pos = atomicAdd(&cnt[d.y], 1); if (pos < CAP) slot[(size_t)d.y*CAP + pos] = (unsigned short)s.y; }
    if (d.z / SEGW == seg){ pos = atomicAdd(&cnt[d.z], 1); if (pos < CAP) slot[(size_t)d.z*CAP + pos] = (unsigned short)s.z; }
    if (d.w / SEGW == seg){ pos = atomicAdd(&cnt[d.w], 1); if (pos < CAP) slot[(size_t)d.w*CAP + pos] = (unsigned short)s.w; }
  }
  // ---- fused prep ----
  if (b == 0){
    int k = threadIdx.x;
    if (k < 64){
      float sa = 0.f, sb = 0.f;
      for (int j = 0; j < 64; ++j){
        float w = W_gat[k*64 + j];
        sa = fmaf(w, a_src[j], sa);
        sb = fmaf(w, a_dst[j], sb);
      }
      va[k] = sa; vb[k] = sb;
    }
  } else if (b <= 9){
    int w = b - 1;
    const float* s; const float* sub = nullptr;
    switch (w){
      case 0: s = W_mlp; break;
      case 1: s = Wr; break;
      case 2: s = W_cheb; sub = W_cheb + 8192; break;   // W0 - W2
      case 3: s = W_gin; break;
      case 4: s = Wl; break;
      case 5: s = W_cheb + 4096; break;                  // W1
      case 6: s = W_cheb + 8192; break;                  // W2
      case 7: s = W_gcn; break;
      default: s = W_gat; break;
    }
    for (int ee = threadIdx.x; ee < 4096; ee += 256){
      int k = ee >> 6, n = ee & 63;
      float f = s[ee];
      if (sub) f -= sub[ee];
      wpk[(size_t)w*4096 + (size_t)n*64 + k] = f2bf(f);
    }
  } else if (b < 3136){
    int i = (b - 10)*256 + threadIdx.x;
    if (i < NN*16){
      float4 v = x4[i];
      ushort4 o;
      o.x = f2bf(v.x); o.y = f2bf(v.y); o.z = f2bf(v.z); o.w = f2bf(v.w);
      xb4[i] = o;
    } else if (i < (NN+1)*16){
      ushort4 z; z.x = 0; z.y = 0; z.z = 0; z.w = 0;
      xb4[i] = z;
      t1b4[i] = z;            // t1b zero row at same row index NN
    }
  }
}

// ---------------- per-node scalars: {dinvc, dinv, el, er} ----------------
__global__ __launch_bounds__(256) void k_nodal(const float* __restrict__ x,
    const int* __restrict__ cnt, const float* __restrict__ va, const float* __restrict__ vb,
    float4* __restrict__ nodal){
  int tid = threadIdx.x;
  int li = tid & 15;
  int row = blockIdx.x*16 + (tid >> 4);
  if (row >= NN) return;
  float4 hv = *(const float4*)&x[(size_t)row*64 + li*4];
  float4 av = *(const float4*)&va[li*4];
  float4 bv = *(const float4*)&vb[li*4];
  float ps = hv.x*av.x + hv.y*av.y + hv.z*av.z + hv.w*av.w;
  float pd = hv.x*bv.x + hv.y*bv.y + hv.z*bv.z + hv.w*bv.w;
  #pragma unroll
  for (int o = 1; o < 16; o <<= 1){ ps += __shfl_xor(ps, o); pd += __shfl_xor(pd, o); }
  if (li == 0){
    float c = (float)cnt[row];
    float dinv  = rsqrtf(c + 1.f);
    float dinvc = rsqrtf(fmaxf(c, 1.f));
    nodal[row] = make_float4(dinvc, dinv, ps, pd);
  }
}

// ---------------- pass A: packed LDS-broadcast gather -> nsb, t1b, v1b, gb, cmb ------
__global__ __launch_bounds__(256) void k_aggA(const float* __restrict__ x,
    const unsigned short* __restrict__ xb,
    const int* __restrict__ cnt, const unsigned short* __restrict__ slot,
    const float4* __restrict__ nodal,
    unsigned* __restrict__ nsb2, unsigned* __restrict__ t1b2,
    unsigned* __restrict__ v1b2, unsigned* __restrict__ gb2,
    unsigned* __restrict__ cmb){
  __shared__ uint2 sU[4][64];
  int wid  = threadIdx.x >> 6;
  int lane = threadIdx.x & 63;
  int node = blockIdx.x*4 + wid;
  if (node >= NN) return;
  int c = min(cnt[node], CAP);
  const unsigned short* sl = slot + (size_t)node*CAP;
  float4 nn = nodal[node];         // {dinvc, dinv, el, er}
  float ern = nn.w;
  int half = lane >> 5, hl = lane & 31;
  float a0e=0.f,a0o=0.f,a1e=0.f,a1o=0.f,a2e=0.f,a2o=0.f,a3e=0.f,a3o=0.f, zl=0.f;
  for (int base = 0; base < c; base += 64){
    int rem = min(64, c - base);
    bool act = lane < rem;
    int s = act ? (int)sl[base+lane] : NN;            // NN = zero row
    float4 ns = act ? nodal[s] : make_float4(0.f,0.f,0.f,0.f);
    float p = act ? __expf(fminf(leaky02(ns.z + ern), 60.f)) : 0.f;
    p = bf2f(f2bf(p));               // round once so z and numerator stay consistent
    zl += p;
    if (act) cmb[(size_t)node*CAP + base + lane] = pack2((unsigned short)s, f2bf(ns.x));
    sU[wid][lane] = make_uint2(pack2((unsigned short)s, f2bf(p)),
                               pack2(f2bf(ns.x), f2bf(ns.y)));
    lds_fence();                   // wave-sync: ds_write visible before broadcast reads
    for (int j = 0; j < rem; j += 16){       // 16 edges = 8 pairs per iteration
      uint2 w[8]; unsigned uv[8];
      #pragma unroll
      for (int q2 = 0; q2 < 8; ++q2){
        w[q2] = sU[wid][j + 2*q2 + half];    // 2 distinct addrs per wave: free 2-way
        unsigned sb = w[q2].x & 0xffffu;
        sb = (sb <= (unsigned)NN) ? sb : NN;            // defensive clamp
        uv[q2] = *(const unsigned*)&xb[(size_t)sb*64 + 2*hl];
      }
      #pragma unroll
      for (int q2 = 0; q2 < 8; ++q2){
        float pb  = bf2f((unsigned short)(w[q2].x >> 16));
        float dcb = bf2f((unsigned short)(w[q2].y & 0xffffu));
        float dvb = bf2f((unsigned short)(w[q2].y >> 16));
        float lo = __uint_as_float(uv[q2] << 16);
        float hi = __uint_as_float(uv[q2] & 0xffff0000u);
        a0e += lo;                       a0o += hi;
        a1e = fmaf(dcb, lo, a1e);        a1o = fmaf(dcb, hi, a1o);
        a2e = fmaf(dvb, lo, a2e);        a2o = fmaf(dvb, hi, a2o);
        a3e = fmaf(pb,  lo, a3e);        a3o = fmaf(pb,  hi, a3o);
      }
    }
    lds_fence();                   // reads done before next chunk overwrites sU
  }
  // combine the two half-waves (each processed alternate edges)
  a0e += __shfl_xor(a0e, 32); a0o += __shfl_xor(a0o, 32);
  a1e += __shfl_xor(a1e, 32); a1o += __shfl_xor(a1o, 32);
  a2e += __shfl_xor(a2e, 32); a2o += __shfl_xor(a2o, 32);
  a3e += __shfl_xor(a3e, 32); a3o += __shfl_xor(a3o, 32);
  #pragma unroll
  for (int o = 32; o > 0; o >>= 1) zl += __shfl_xor(zl, o);
  float2 xs = *(const float2*)&x[(size_t)node*64 + 2*hl];   // self terms exact (fp32)
  float p_self = __expf(fminf(leaky02(nn.z + nn.w), 60.f));
  float rz = 1.f / (zl + p_self + 1e-16f);
  size_t off2 = (size_t)node*32 + hl;
  if (half == 0){
    nsb2[off2] = pack2(f2bf(a0e), f2bf(a0o));
    t1b2[off2] = pack2(f2bf(-nn.x*a1e), f2bf(-nn.x*a1o));
  } else {
    v1b2[off2] = pack2(f2bf(nn.y*a2e + nn.y*nn.y*xs.x), f2bf(nn.y*a2o + nn.y*nn.y*xs.y));
    gb2[off2]  = pack2(f2bf((a3e + p_self*xs.x)*rz), f2bf((a3o + p_self*xs.y)*rz));
  }
}

// ---------------- pass B: cmb-driven gather of t1b -> ub ----------------
__global__ __launch_bounds__(256) void k_aggB(const unsigned short* __restrict__ t1b,
    const int* __restrict__ cnt, const unsigned* __restrict__ cmb,
    const float4* __restrict__ nodal, unsigned* __restrict__ ub2){
  __shared__ unsigned sB[4][64];
  int wid  = threadIdx.x >> 6;
  int lane = threadIdx.x & 63;
  int node = blockIdx.x*4 + wid;
  if (node >= NN) return;
  int c = min(cnt[node], CAP);
  int half = lane >> 5, hl = lane & 31;
  float ae = 0.f, ao = 0.f;
  for (int base = 0; base < c; base += 64){
    int rem = min(64, c - base);
    bool act = lane < rem;
    unsigned cw = act ? cmb[(size_t)node*CAP + base + lane] : pack2(NN, 0);
    sB[wid][lane] = cw;
    lds_fence();
    for (int j = 0; j < rem; j += 16){       // 16 edges = 8 pairs
      unsigned w[8]; unsigned uv[8];
      #pragma unroll
      for (int q2 = 0; q2 < 8; ++q2){
        w[q2] = sB[wid][j + 2*q2 + half];
        unsigned sb = w[q2] & 0xffffu;
        sb = (sb <= (unsigned)NN) ? sb : NN;
        uv[q2] = *(const unsigned*)&t1b[(size_t)sb*64 + 2*hl];
      }
      #pragma unroll
      for (int q2 = 0; q2 < 8; ++q2){
        float dc = bf2f((unsigned short)(w[q2] >> 16));
        float lo = __uint_as_float(uv[q2] << 16);
        float hi = __uint_as_float(uv[q2] & 0xffff0000u);
        ae = fmaf(dc, lo, ae);
        ao = fmaf(dc, hi, ao);
      }
    }
    lds_fence();
  }
  ae += __shfl_xor(ae, 32);
  ao += __shfl_xor(ao, 32);
  if (half == 0){
    float sc = -2.f * nodal[node].x;
    ub2[(size_t)node*32 + hl] = pack2(f2bf(sc*ae), f2bf(sc*ao));
  }
}

// ---------------- epilogue: barrier-free, LDS-free bf16 MFMA, 1 wave/block --------
__global__ __launch_bounds__(64) void k_epi(
    const float* __restrict__ wts,
    const float* __restrict__ b_mlp, const float* __restrict__ b_sage,
    const float* __restrict__ b_gcn, const float* __restrict__ b_gat,
    const float* __restrict__ b_cheb, const float* __restrict__ b_gin,
    const float4* __restrict__ nodal, const unsigned short* __restrict__ wpk,
    const unsigned short* __restrict__ xb, const unsigned short* __restrict__ nsb,
    const unsigned short* __restrict__ t1b, const unsigned short* __restrict__ v1b,
    const unsigned short* __restrict__ gb, const unsigned short* __restrict__ ub,
    float* __restrict__ out){
  const int lane = threadIdx.x;
  const int ml   = lane & 15;          // MFMA m / n / col index
  const int q    = lane >> 4;          // quad
  const int rowbase = blockIdx.x*16;
  const float w0 = wts[0], w1 = wts[1], w2 = wts[2], w3 = wts[3], w4 = wts[4], w5 = wts[5];
  const float* nod = (const float*)nodal;

  short8 ah0, ah1;

  auto loadA = [&](const unsigned short* __restrict__ src){
    const unsigned short* p = src + (size_t)(rowbase + ml)*64 + q*8;
    ah0 = *(const short8*)p;
    ah1 = *(const short8*)(p + 32);
  };
  auto group = [&](int w, f32x4 acc[4]){
    const unsigned short* base = wpk + (size_t)w*4096;
    #pragma unroll
    for (int nt = 0; nt < 4; ++nt){
      const unsigned short* bp = base + (size_t)(nt*16 + ml)*64;
      short8 b0 = *(const short8*)(bp + q*8);
      short8 b1 = *(const short8*)(bp + 32 + q*8);
      acc[nt] = __builtin_amdgcn_mfma_f32_16x16x32_bf16(ah0, b0, acc[nt], 0, 0, 0);
      acc[nt] = __builtin_amdgcn_mfma_f32_16x16x32_bf16(ah1, b1, acc[nt], 0, 0, 0);
    }
  };

  f32x4 res[4];
  #pragma unroll
  for (int i = 0; i < 4; ++i) res[i] = (f32x4){0.f,0.f,0.f,0.f};

  auto emit = [&](const f32x4 acc[4], const float* __restrict__ bias, float wk){
    #pragma unroll
    for (int nt = 0; nt < 4; ++nt){
      float b = bias[nt*16 + ml];
      #pragma unroll
      for (int r = 0; r < 4; ++r) res[nt][r] += wk * eluf(acc[nt][r] + b);
    }
  };

  f32x4 t[4], accC[4], accWr[4], accG[4];

  // gcn
  loadA(v1b);
  #pragma unroll
  for (int i=0;i<4;++i) t[i] = (f32x4){0.f,0.f,0.f,0.f};
  group(7, t); emit(t, b_gcn, w2);
  // gat
  loadA(gb);
  #pragma unroll
  for (int i=0;i<4;++i) t[i] = (f32x4){0.f,0.f,0.f,0.f};
  group(8, t); emit(t, b_gat, w3);
  // cheb partials: u@W2, T1@W1
  loadA(ub);
  #pragma unroll
  for (int i=0;i<4;++i) accC[i] = (f32x4){0.f,0.f,0.f,0.f};
  group(6, accC);
  loadA(t1b);
  group(5, accC);
  // A = x: mlp, Wr, W0-W2 (finish cheb), gin-start
  loadA(xb);
  #pragma unroll
  for (int i=0;i<4;++i) t[i] = (f32x4){0.f,0.f,0.f,0.f};
  group(0, t); emit(t, b_mlp, w0);
  #pragma unroll
  for (int i=0;i<4;++i) accWr[i] = (f32x4){0.f,0.f,0.f,0.f};
  group(1, accWr);
  group(2, accC); emit(accC, b_cheb, w4);
  #pragma unroll
  for (int i=0;i<4;++i) accG[i] = (f32x4){0.f,0.f,0.f,0.f};
  group(3, accG);
  // A = nsum: finish gin, then sage
  loadA(nsb);
  group(3, accG); emit(accG, b_gin, w5);
  #pragma unroll
  for (int i=0;i<4;++i) t[i] = (f32x4){0.f,0.f,0.f,0.f};
  group(4, t);
  #pragma unroll
  for (int nt = 0; nt < 4; ++nt){
    float b = b_sage[nt*16 + ml];
    #pragma unroll
    for (int r = 0; r < 4; ++r){
      int row = rowbase + q*4 + r;
      float dc = nod[(size_t)row*4];     // dinvc
      float invd = dc*dc;                // 1/max(deg,1)
      res[nt][r] += w1 * eluf(invd*t[nt][r] + accWr[nt][r] + b);
    }
  }
  // store (C/D layout: col=lane&15, row=q*4+r)
  #pragma unroll
  for (int nt = 0; nt < 4; ++nt){
    int col = nt*16 + ml;
    #pragma unroll
    for (int r = 0; r < 4; ++r){
      int row = rowbase + q*4 + r;
      out[(size_t)row*64 + col] = res[nt][r];
    }
  }
}

extern "C" void kernel_launch(void* const* d_in, const int* in_sizes, int n_in,
                              void* d_out, int out_size, void* d_ws, size_t ws_size,
                              hipStream_t stream){
  const float* x      = (const float*)d_in[0];
  const float* wts    = (const float*)d_in[1];
  const float* W_mlp  = (const float*)d_in[2];
  const float* b_mlp  = (const float*)d_in[3];
  const float* Wl     = (const float*)d_in[4];
  const float* Wr     = (const float*)d_in[5];
  const float* b_sage = (const float*)d_in[6];
  const float* W_gcn  = (const float*)d_in[7];
  const float* b_gcn  = (const float*)d_in[8];
  const float* W_gat  = (const float*)d_in[9];
  const float* a_src  = (const float*)d_in[10];
  const float* a_dst  = (const float*)d_in[11];
  const float* b_gat  = (const float*)d_in[12];
  const float* W_cheb = (const float*)d_in[13];
  const float* b_cheb = (const float*)d_in[14];
  const float* W_gin  = (const float*)d_in[15];
  const float* b_gin  = (const float*)d_in[16];
  const int*   ei     = (const int*)d_in[17];

  float* wsf  = (float*)d_ws;
  int*  cnt   = (int*)d_ws;
  unsigned short* slot = (unsigned short*)(wsf + O_SLOT);
  float4* nodal = (float4*)(wsf + O_NODAL);
  float* va   = wsf + O_VA;
  float* vb   = wsf + O_VB;
  unsigned short* xbu = (unsigned short*)(wsf + O_XB);
  unsigned short* nsb = (unsigned short*)(wsf + O_NSB);
  unsigned short* t1b = (unsigned short*)(wsf + O_T1B);
  unsigned short* v1b = (unsigned short*)(wsf + O_V1B);
  unsigned short* gb  = (unsigned short*)(wsf + O_GB);
  unsigned short* ub  = (unsigned short*)(wsf + O_UB);
  unsigned short* wpk = (unsigned short*)(wsf + O_WPK);
  unsigned* cmb = (unsigned*)(wsf + O_CMB);
  float* out  = (float*)d_out;

  hipMemsetAsync(cnt, 0, NN*sizeof(int), stream);
  k_scatter <<<6256, 256, 0, stream>>>((const int4*)ei, (const int4*)(ei + NE), cnt, slot,
                                       W_mlp, Wr, W_cheb, W_gin, Wl, W_gcn, W_gat,
                                       a_src, a_dst, (const float4*)x,
                                       va, vb, wpk, (ushort4*)xbu, (ushort4*)t1b);
  k_nodal   <<<3125, 256, 0, stream>>>(x, cnt, va, vb, nodal);
  k_aggA    <<<12500,256, 0, stream>>>(x, xbu, cnt, slot, nodal,
                                       (unsigned*)nsb, (unsigned*)t1b,
                                       (unsigned*)v1b, (unsigned*)gb, cmb);
  k_aggB    <<<12500,256, 0, stream>>>(t1b, cnt, cmb, nodal, (unsigned*)ub);
  k_epi     <<<3125,  64, 0, stream>>>(wts, b_mlp, b_sage, b_gcn, b_gat, b_cheb, b_gin,
                                       nodal, wpk, xbu, nsb, t1b, v1b, gb, ub, out);
}

// Round 11
// 228.112 us; speedup vs baseline: 1.0201x; 1.0201x over previous
//
#include <hip/hip_runtime.h>
#include <cstdint>
#include <cstddef>

#define NN 50000
#define NE 800000
#define CAP 96      // max in-degree bucket (Poisson(16): P(deg>=96) ~ 1e-42)
#define NSEG 8      // dst-range segments (XCD-aligned via blockIdx&7)
#define SEGW 6250   // NN / NSEG

// ---------------- ws layout (units of 4 bytes) ----------------
constexpr size_t O_CNT   = 0;                        // int[NN]
constexpr size_t O_SLOT  = 50048;                    // ushort[NN*CAP] (region kept int-sized)
constexpr size_t O_NODAL = O_SLOT + (size_t)NN*CAP;  // float4[NN] {dinvc,dinv,el,er}
constexpr size_t O_VA    = O_NODAL + 200000;         // 64
constexpr size_t O_VB    = O_VA + 64;                // 64
constexpr size_t O_XB    = O_VB + 64;                // ushort[(NN+1)*64] bf16 x (+zero row)
constexpr size_t O_NSB   = O_XB + 1600032;           // ushort[NN*64] bf16 nsum
constexpr size_t O_T1B   = O_NSB + 1600000;          // ushort[(NN+1)*64] bf16 T1 (+zero row)
constexpr size_t O_V1B   = O_T1B + 1600032;          // ushort[NN*64]
constexpr size_t O_GB    = O_V1B + 1600000;          // ushort[NN*64]
constexpr size_t O_UB    = O_GB  + 1600000;          // ushort[NN*64]
constexpr size_t O_WPK   = O_UB  + 1600000;          // ushort[9*4096] bf16 weights
// total ~59 MB

typedef __attribute__((ext_vector_type(8))) short short8;   // 8 bf16 (4 VGPRs)
typedef __attribute__((ext_vector_type(4))) float f32x4;

__device__ __forceinline__ float leaky02(float v){ return v >= 0.f ? v : 0.2f*v; }
__device__ __forceinline__ float eluf(float v){ return v > 0.f ? v : (__expf(v) - 1.f); }

// intra-wave LDS producer->consumer fence (wave-synchronous pattern)
__device__ __forceinline__ void lds_fence(){
  asm volatile("s_waitcnt lgkmcnt(0)" ::: "memory");
}

__device__ __forceinline__ unsigned short f2bf(float f){   // round-to-nearest-even
  unsigned u = __float_as_uint(f);
  unsigned r = (u + 0x7FFFu + ((u >> 16) & 1u)) >> 16;
  return (unsigned short)r;
}
__device__ __forceinline__ float bf2f(unsigned short b){
  return __uint_as_float(((unsigned)b) << 16);
}
__device__ __forceinline__ unsigned pack2(unsigned short lo, unsigned short hi){
  return (unsigned)lo | ((unsigned)hi << 16);
}

// ---------------- fused: XCD-segmented bucket build + prep (va/wpk/xcast) ----------
// grid 25000: seg = b&7 commits only dst in [seg*6250,(seg+1)*6250) -> per-XCD slot
// region 1.2 MB stays L2-resident (kills write amplification). First 3136 blocks
// additionally run the prep work in scatter's idle pipes.
__global__ __launch_bounds__(256) void k_scatter(
    const int* __restrict__ src, const int* __restrict__ dst,
    int* __restrict__ cnt, unsigned short* __restrict__ slot,
    const float* __restrict__ W_mlp, const float* __restrict__ Wr,
    const float* __restrict__ W_cheb, const float* __restrict__ W_gin,
    const float* __restrict__ Wl, const float* __restrict__ W_gcn,
    const float* __restrict__ W_gat,
    const float* __restrict__ a_src, const float* __restrict__ a_dst,
    const float4* __restrict__ x4,
    float* __restrict__ va, float* __restrict__ vb,
    unsigned short* __restrict__ wpk,
    ushort4* __restrict__ xb4, ushort4* __restrict__ t1b4){
  int b = blockIdx.x;
  int seg = b & (NSEG-1);
  int lo = seg * SEGW;           // range compare instead of divide
  int e = (b >> 3)*256 + threadIdx.x;
  if (e < NE){
    int d = dst[e];
    if (d >= lo && d < lo + SEGW){
      int s = src[e];
      int pos = atomicAdd(&cnt[d], 1);
      if (pos < CAP) slot[(size_t)d*CAP + pos] = (unsigned short)s;
    }
  }
  // ---- fused prep ----
  if (b == 0){
    int k = threadIdx.x;
    if (k < 64){
      float sa = 0.f, sb = 0.f;
      for (int j = 0; j < 64; ++j){
        float w = W_gat[k*64 + j];
        sa = fmaf(w, a_src[j], sa);
        sb = fmaf(w, a_dst[j], sb);
      }
      va[k] = sa; vb[k] = sb;
    }
  } else if (b <= 9){
    int w = b - 1;
    const float* s; const float* sub = nullptr;
    switch (w){
      case 0: s = W_mlp; break;
      case 1: s = Wr; break;
      case 2: s = W_cheb; sub = W_cheb + 8192; break;   // W0 - W2
      case 3: s = W_gin; break;
      case 4: s = Wl; break;
      case 5: s = W_cheb + 4096; break;                  // W1
      case 6: s = W_cheb + 8192; break;                  // W2
      case 7: s = W_gcn; break;
      default: s = W_gat; break;
    }
    for (int ee = threadIdx.x; ee < 4096; ee += 256){
      int k = ee >> 6, n = ee & 63;
      float f = s[ee];
      if (sub) f -= sub[ee];
      wpk[(size_t)w*4096 + (size_t)n*64 + k] = f2bf(f);
    }
  } else if (b < 3136){
    int i = (b - 10)*256 + threadIdx.x;
    if (i < NN*16){
      float4 v = x4[i];
      ushort4 o;
      o.x = f2bf(v.x); o.y = f2bf(v.y); o.z = f2bf(v.z); o.w = f2bf(v.w);
      xb4[i] = o;
    } else if (i < (NN+1)*16){
      ushort4 z; z.x = 0; z.y = 0; z.z = 0; z.w = 0;
      xb4[i] = z;
      t1b4[i] = z;            // t1b zero row at same row index NN
    }
  }
}

// ---------------- per-node scalars: {dinvc, dinv, el, er} ----------------
__global__ __launch_bounds__(256) void k_nodal(const float* __restrict__ x,
    const int* __restrict__ cnt, const float* __restrict__ va, const float* __restrict__ vb,
    float4* __restrict__ nodal){
  int tid = threadIdx.x;
  int li = tid & 15;
  int row = blockIdx.x*16 + (tid >> 4);
  if (row >= NN) return;
  float4 hv = *(const float4*)&x[(size_t)row*64 + li*4];
  float4 av = *(const float4*)&va[li*4];
  float4 bv = *(const float4*)&vb[li*4];
  float ps = hv.x*av.x + hv.y*av.y + hv.z*av.z + hv.w*av.w;
  float pd = hv.x*bv.x + hv.y*bv.y + hv.z*bv.z + hv.w*bv.w;
  #pragma unroll
  for (int o = 1; o < 16; o <<= 1){ ps += __shfl_xor(ps, o); pd += __shfl_xor(pd, o); }
  if (li == 0){
    float c = (float)cnt[row];
    float dinv  = rsqrtf(c + 1.f);
    float dinvc = rsqrtf(fmaxf(c, 1.f));
    nodal[row] = make_float4(dinvc, dinv, ps, pd);
  }
}

// ---------------- pass A: edge-pair LDS-broadcast gather -> nsb, t1b, v1b, gb --------
__global__ __launch_bounds__(256) void k_aggA(const float* __restrict__ x,
    const unsigned short* __restrict__ xb,
    const int* __restrict__ cnt, const unsigned short* __restrict__ slot,
    const float4* __restrict__ nodal,
    unsigned* __restrict__ nsb2, unsigned* __restrict__ t1b2,
    unsigned* __restrict__ v1b2, unsigned* __restrict__ gb2){
  __shared__ float4 sW[4][64];
  int wid  = threadIdx.x >> 6;
  int lane = threadIdx.x & 63;
  int node = blockIdx.x*4 + wid;
  if (node >= NN) return;
  int c = min(cnt[node], CAP);
  const unsigned short* sl = slot + (size_t)node*CAP;
  float4 nn = nodal[node];         // {dinvc, dinv, el, er}
  float ern = nn.w;
  int half = lane >> 5, hl = lane & 31;
  float a0e=0.f,a0o=0.f,a1e=0.f,a1o=0.f,a2e=0.f,a2o=0.f,a3e=0.f,a3o=0.f, zl=0.f;
  for (int base = 0; base < c; base += 64){
    int rem = min(64, c - base);
    bool act = lane < rem;
    int s = act ? (int)sl[base+lane] : NN;            // NN = zero row
    float4 ns = act ? nodal[s] : make_float4(0.f,0.f,0.f,0.f);
    float p = act ? __expf(fminf(leaky02(ns.z + ern), 60.f)) : 0.f;
    zl += p;
    sW[wid][lane] = make_float4(__int_as_float(s), ns.x, ns.y, p);
    lds_fence();                   // wave-sync: ds_write visible before broadcast reads
    for (int j = 0; j < rem; j += 8){        // 8 edges = 4 pairs per iteration
      float4 w[4]; unsigned uv[4];
      #pragma unroll
      for (int q2 = 0; q2 < 4; ++q2){
        w[q2] = sW[wid][j + 2*q2 + half];    // 2 distinct addrs per wave: free 2-way
        int sb = __float_as_int(w[q2].x);
        sb = ((unsigned)sb <= (unsigned)NN) ? sb : NN;   // defensive clamp
        uv[q2] = *(const unsigned*)&xb[(size_t)sb*64 + 2*hl];
      }
      #pragma unroll
      for (int q2 = 0; q2 < 4; ++q2){
        float lo = __uint_as_float(uv[q2] << 16);
        float hi = __uint_as_float(uv[q2] & 0xffff0000u);
        a0e += lo;                       a0o += hi;
        a1e = fmaf(w[q2].y, lo, a1e);    a1o = fmaf(w[q2].y, hi, a1o);
        a2e = fmaf(w[q2].z, lo, a2e);    a2o = fmaf(w[q2].z, hi, a2o);
        a3e = fmaf(w[q2].w, lo, a3e);    a3o = fmaf(w[q2].w, hi, a3o);
      }
    }
    lds_fence();                   // reads done before next chunk overwrites sW
  }
  // combine the two half-waves (each processed alternate edges)
  a0e += __shfl_xor(a0e, 32); a0o += __shfl_xor(a0o, 32);
  a1e += __shfl_xor(a1e, 32); a1o += __shfl_xor(a1o, 32);
  a2e += __shfl_xor(a2e, 32); a2o += __shfl_xor(a2o, 32);
  a3e += __shfl_xor(a3e, 32); a3o += __shfl_xor(a3o, 32);
  #pragma unroll
  for (int o = 32; o > 0; o >>= 1) zl += __shfl_xor(zl, o);
  float2 xs = *(const float2*)&x[(size_t)node*64 + 2*hl];   // self terms exact (fp32)
  float p_self = __expf(fminf(leaky02(nn.z + nn.w), 60.f));
  float rz = 1.f / (zl + p_self + 1e-16f);
  size_t off2 = (size_t)node*32 + hl;
  if (half == 0){
    nsb2[off2] = pack2(f2bf(a0e), f2bf(a0o));
    t1b2[off2] = pack2(f2bf(-nn.x*a1e), f2bf(-nn.x*a1o));
  } else {
    v1b2[off2] = pack2(f2bf(nn.y*a2e + nn.y*nn.y*xs.x), f2bf(nn.y*a2o + nn.y*nn.y*xs.y));
    gb2[off2]  = pack2(f2bf((a3e + p_self*xs.x)*rz), f2bf((a3o + p_self*xs.y)*rz));
  }
}

// ---------------- pass B: edge-pair gather of t1b -> ub ----------------
__global__ __launch_bounds__(256) void k_aggB(const unsigned short* __restrict__ t1b,
    const int* __restrict__ cnt, const unsigned short* __restrict__ slot,
    const float4* __restrict__ nodal, unsigned* __restrict__ ub2){
  __shared__ float2 sW[4][64];
  int wid  = threadIdx.x >> 6;
  int lane = threadIdx.x & 63;
  int node = blockIdx.x*4 + wid;
  if (node >= NN) return;
  int c = min(cnt[node], CAP);
  const unsigned short* sl = slot + (size_t)node*CAP;
  const float* nf = (const float*)nodal;
  int half = lane >> 5, hl = lane & 31;
  float ae = 0.f, ao = 0.f;
  for (int base = 0; base < c; base += 64){
    int rem = min(64, c - base);
    bool act = lane < rem;
    int s = act ? (int)sl[base+lane] : NN;            // NN = zero row
    float dc = act ? nf[(size_t)s*4] : 0.f;
    sW[wid][lane] = make_float2(__int_as_float(s), dc);
    lds_fence();
    for (int j = 0; j < rem; j += 8){        // 8 edges = 4 pairs
      float2 w[4]; unsigned uv[4];
      #pragma unroll
      for (int q2 = 0; q2 < 4; ++q2){
        w[q2] = sW[wid][j + 2*q2 + half];
        int sb = __float_as_int(w[q2].x);
        sb = ((unsigned)sb <= (unsigned)NN) ? sb : NN;
        uv[q2] = *(const unsigned*)&t1b[(size_t)sb*64 + 2*hl];
      }
      #pragma unroll
      for (int q2 = 0; q2 < 4; ++q2){
        float lo = __uint_as_float(uv[q2] << 16);
        float hi = __uint_as_float(uv[q2] & 0xffff0000u);
        ae = fmaf(w[q2].y, lo, ae);
        ao = fmaf(w[q2].y, hi, ao);
      }
    }
    lds_fence();
  }
  ae += __shfl_xor(ae, 32);
  ao += __shfl_xor(ao, 32);
  if (half == 0){
    float sc = -2.f * nodal[node].x;
    ub2[(size_t)node*32 + hl] = pack2(f2bf(sc*ae), f2bf(sc*ao));
  }
}

// ---------------- epilogue: barrier-free, LDS-free bf16 MFMA, 1 wave/block --------
__global__ __launch_bounds__(64) void k_epi(
    const float* __restrict__ wts,
    const float* __restrict__ b_mlp, const float* __restrict__ b_sage,
    const float* __restrict__ b_gcn, const float* __restrict__ b_gat,
    const float* __restrict__ b_cheb, const float* __restrict__ b_gin,
    const float4* __restrict__ nodal, const unsigned short* __restrict__ wpk,
    const unsigned short* __restrict__ xb, const unsigned short* __restrict__ nsb,
    const unsigned short* __restrict__ t1b, const unsigned short* __restrict__ v1b,
    const unsigned short* __restrict__ gb, const unsigned short* __restrict__ ub,
    float* __restrict__ out){
  const int lane = threadIdx.x;
  const int ml   = lane & 15;          // MFMA m / n / col index
  const int q    = lane >> 4;          // quad
  const int rowbase = blockIdx.x*16;
  const float w0 = wts[0], w1 = wts[1], w2 = wts[2], w3 = wts[3], w4 = wts[4], w5 = wts[5];
  const float* nod = (const float*)nodal;

  short8 ah0, ah1;

  auto loadA = [&](const unsigned short* __restrict__ src){
    const unsigned short* p = src + (size_t)(rowbase + ml)*64 + q*8;
    ah0 = *(const short8*)p;
    ah1 = *(const short8*)(p + 32);
  };
  auto group = [&](int w, f32x4 acc[4]){
    const unsigned short* base = wpk + (size_t)w*4096;
    #pragma unroll
    for (int nt = 0; nt < 4; ++nt){
      const unsigned short* bp = base + (size_t)(nt*16 + ml)*64;
      short8 b0 = *(const short8*)(bp + q*8);
      short8 b1 = *(const short8*)(bp + 32 + q*8);
      acc[nt] = __builtin_amdgcn_mfma_f32_16x16x32_bf16(ah0, b0, acc[nt], 0, 0, 0);
      acc[nt] = __builtin_amdgcn_mfma_f32_16x16x32_bf16(ah1, b1, acc[nt], 0, 0, 0);
    }
  };

  f32x4 res[4];
  #pragma unroll
  for (int i = 0; i < 4; ++i) res[i] = (f32x4){0.f,0.f,0.f,0.f};

  auto emit = [&](const f32x4 acc[4], const float* __restrict__ bias, float wk){
    #pragma unroll
    for (int nt = 0; nt < 4; ++nt){
      float b = bias[nt*16 + ml];
      #pragma unroll
      for (int r = 0; r < 4; ++r) res[nt][r] += wk * eluf(acc[nt][r] + b);
    }
  };

  f32x4 t[4], accC[4], accWr[4], accG[4];

  // gcn
  loadA(v1b);
  #pragma unroll
  for (int i=0;i<4;++i) t[i] = (f32x4){0.f,0.f,0.f,0.f};
  group(7, t); emit(t, b_gcn, w2);
  // gat
  loadA(gb);
  #pragma unroll
  for (int i=0;i<4;++i) t[i] = (f32x4){0.f,0.f,0.f,0.f};
  group(8, t); emit(t, b_gat, w3);
  // cheb partials: u@W2, T1@W1
  loadA(ub);
  #pragma unroll
  for (int i=0;i<4;++i) accC[i] = (f32x4){0.f,0.f,0.f,0.f};
  group(6, accC);
  loadA(t1b);
  group(5, accC);
  // A = x: mlp, Wr, W0-W2 (finish cheb), gin-start
  loadA(xb);
  #pragma unroll
  for (int i=0;i<4;++i) t[i] = (f32x4){0.f,0.f,0.f,0.f};
  group(0, t); emit(t, b_mlp, w0);
  #pragma unroll
  for (int i=0;i<4;++i) accWr[i] = (f32x4){0.f,0.f,0.f,0.f};
  group(1, accWr);
  group(2, accC); emit(accC, b_cheb, w4);
  #pragma unroll
  for (int i=0;i<4;++i) accG[i] = (f32x4){0.f,0.f,0.f,0.f};
  group(3, accG);
  // A = nsum: finish gin, then sage
  loadA(nsb);
  group(3, accG); emit(accG, b_gin, w5);
  #pragma unroll
  for (int i=0;i<4;++i) t[i] = (f32x4){0.f,0.f,0.f,0.f};
  group(4, t);
  #pragma unroll
  for (int nt = 0; nt < 4; ++nt){
    float b = b_sage[nt*16 + ml];
    #pragma unroll
    for (int r = 0; r < 4; ++r){
      int row = rowbase + q*4 + r;
      float dc = nod[(size_t)row*4];     // dinvc
      float invd = dc*dc;                // 1/max(deg,1)
      res[nt][r] += w1 * eluf(invd*t[nt][r] + accWr[nt][r] + b);
    }
  }
  // store (C/D layout: col=lane&15, row=q*4+r)
  #pragma unroll
  for (int nt = 0; nt < 4; ++nt){
    int col = nt*16 + ml;
    #pragma unroll
    for (int r = 0; r < 4; ++r){
      int row = rowbase + q*4 + r;
      out[(size_t)row*64 + col] = res[nt][r];
    }
  }
}

extern "C" void kernel_launch(void* const* d_in, const int* in_sizes, int n_in,
                              void* d_out, int out_size, void* d_ws, size_t ws_size,
                              hipStream_t stream){
  const float* x      = (const float*)d_in[0];
  const float* wts    = (const float*)d_in[1];
  const float* W_mlp  = (const float*)d_in[2];
  const float* b_mlp  = (const float*)d_in[3];
  const float* Wl     = (const float*)d_in[4];
  const float* Wr     = (const float*)d_in[5];
  const float* b_sage = (const float*)d_in[6];
  const float* W_gcn  = (const float*)d_in[7];
  const float* b_gcn  = (const float*)d_in[8];
  const float* W_gat  = (const float*)d_in[9];
  const float* a_src  = (const float*)d_in[10];
  const float* a_dst  = (const float*)d_in[11];
  const float* b_gat  = (const float*)d_in[12];
  const float* W_cheb = (const float*)d_in[13];
  const float* b_cheb = (const float*)d_in[14];
  const float* W_gin  = (const float*)d_in[15];
  const float* b_gin  = (const float*)d_in[16];
  const int*   ei     = (const int*)d_in[17];

  float* wsf  = (float*)d_ws;
  int*  cnt   = (int*)d_ws;
  unsigned short* slot = (unsigned short*)(wsf + O_SLOT);
  float4* nodal = (float4*)(wsf + O_NODAL);
  float* va   = wsf + O_VA;
  float* vb   = wsf + O_VB;
  unsigned short* xbu = (unsigned short*)(wsf + O_XB);
  unsigned short* nsb = (unsigned short*)(wsf + O_NSB);
  unsigned short* t1b = (unsigned short*)(wsf + O_T1B);
  unsigned short* v1b = (unsigned short*)(wsf + O_V1B);
  unsigned short* gb  = (unsigned short*)(wsf + O_GB);
  unsigned short* ub  = (unsigned short*)(wsf + O_UB);
  unsigned short* wpk = (unsigned short*)(wsf + O_WPK);
  float* out  = (float*)d_out;

  hipMemsetAsync(cnt, 0, NN*sizeof(int), stream);
  k_scatter <<<25000,256, 0, stream>>>(ei, ei + NE, cnt, slot,
                                       W_mlp, Wr, W_cheb, W_gin, Wl, W_gcn, W_gat,
                                       a_src, a_dst, (const float4*)x,
                                       va, vb, wpk, (ushort4*)xbu, (ushort4*)t1b);
  k_nodal   <<<3125, 256, 0, stream>>>(x, cnt, va, vb, nodal);
  k_aggA    <<<12500,256, 0, stream>>>(x, xbu, cnt, slot, nodal,
                                       (unsigned*)nsb, (unsigned*)t1b,
                                       (unsigned*)v1b, (unsigned*)gb);
  k_aggB    <<<12500,256, 0, stream>>>(t1b, cnt, slot, nodal, (unsigned*)ub);
  k_epi     <<<3125,  64, 0, stream>>>(wts, b_mlp, b_sage, b_gcn, b_gat, b_cheb, b_gin,
                                       nodal, wpk, xbu, nsb, t1b, v1b, gb, ub, out);
}

// Round 12
// 219.547 us; speedup vs baseline: 1.0599x; 1.0390x over previous
//
#include <hip/hip_runtime.h>
#include <cstdint>
#include <cstddef>

#define NN 50000
#define NE 800000
#define CAP 96      // max in-degree bucket (Poisson(16): P(deg>=96) ~ 1e-42)
#define NSEG 8      // dst-range segments (XCD-aligned via blockIdx&7)
#define SEGW 6250   // NN / NSEG

// ---------------- ws layout (units of 4 bytes) ----------------
constexpr size_t O_CNT   = 0;                        // int[NN]
constexpr size_t O_SLOT  = 50048;                    // ushort[NN*CAP] (region kept int-sized)
constexpr size_t O_NODAL = O_SLOT + (size_t)NN*CAP;  // float4[NN] {dinvc,dinv,el,er}
constexpr size_t O_VA    = O_NODAL + 200000;         // 64
constexpr size_t O_VB    = O_VA + 64;                // 64
constexpr size_t O_XB    = O_VB + 64;                // ushort[(NN+1)*64] bf16 x (+zero row)
constexpr size_t O_NSB   = O_XB + 1600032;           // ushort[NN*64] bf16 nsum
constexpr size_t O_T1B   = O_NSB + 1600000;          // ushort[(NN+1)*64] bf16 T1 (+zero row)
constexpr size_t O_V1B   = O_T1B + 1600032;          // ushort[NN*64]
constexpr size_t O_GB    = O_V1B + 1600000;          // ushort[NN*64]
constexpr size_t O_UB    = O_GB  + 1600000;          // ushort[NN*64]
constexpr size_t O_WPK   = O_UB  + 1600000;          // ushort[9*4096] bf16 weights
// total ~59 MB

typedef __attribute__((ext_vector_type(8))) short short8;   // 8 bf16 (4 VGPRs)
typedef __attribute__((ext_vector_type(4))) float f32x4;

__device__ __forceinline__ float leaky02(float v){ return v >= 0.f ? v : 0.2f*v; }
__device__ __forceinline__ float eluf(float v){ return v > 0.f ? v : (__expf(v) - 1.f); }

// intra-wave LDS producer->consumer fence (wave-synchronous pattern)
__device__ __forceinline__ void lds_fence(){
  asm volatile("s_waitcnt lgkmcnt(0)" ::: "memory");
}

__device__ __forceinline__ unsigned short f2bf(float f){   // round-to-nearest-even
  unsigned u = __float_as_uint(f);
  unsigned r = (u + 0x7FFFu + ((u >> 16) & 1u)) >> 16;
  return (unsigned short)r;
}
__device__ __forceinline__ float bf2f(unsigned short b){
  return __uint_as_float(((unsigned)b) << 16);
}
__device__ __forceinline__ unsigned pack2(unsigned short lo, unsigned short hi){
  return (unsigned)lo | ((unsigned)hi << 16);
}

// ---------------- fused: XCD-segmented bucket build + prep (va/wpk/xcast) ----------
__global__ __launch_bounds__(256) void k_scatter(
    const int* __restrict__ src, const int* __restrict__ dst,
    int* __restrict__ cnt, unsigned short* __restrict__ slot,
    const float* __restrict__ W_mlp, const float* __restrict__ Wr,
    const float* __restrict__ W_cheb, const float* __restrict__ W_gin,
    const float* __restrict__ Wl, const float* __restrict__ W_gcn,
    const float* __restrict__ W_gat,
    const float* __restrict__ a_src, const float* __restrict__ a_dst,
    const float4* __restrict__ x4,
    float* __restrict__ va, float* __restrict__ vb,
    unsigned short* __restrict__ wpk,
    ushort4* __restrict__ xb4, ushort4* __restrict__ t1b4){
  int b = blockIdx.x;
  int seg = b & (NSEG-1);
  int lo = seg * SEGW;           // range compare instead of divide
  int e = (b >> 3)*256 + threadIdx.x;
  if (e < NE){
    int d = dst[e];
    if (d >= lo && d < lo + SEGW){
      int s = src[e];
      int pos = atomicAdd(&cnt[d], 1);
      if (pos < CAP) slot[(size_t)d*CAP + pos] = (unsigned short)s;
    }
  }
  // ---- fused prep ----
  if (b == 0){
    int k = threadIdx.x;
    if (k < 64){
      float sa = 0.f, sb = 0.f;
      for (int j = 0; j < 64; ++j){
        float w = W_gat[k*64 + j];
        sa = fmaf(w, a_src[j], sa);
        sb = fmaf(w, a_dst[j], sb);
      }
      va[k] = sa; vb[k] = sb;
    }
  } else if (b <= 9){
    int w = b - 1;
    const float* s; const float* sub = nullptr;
    switch (w){
      case 0: s = W_mlp; break;
      case 1: s = Wr; break;
      case 2: s = W_cheb; sub = W_cheb + 8192; break;   // W0 - W2
      case 3: s = W_gin; break;
      case 4: s = Wl; break;
      case 5: s = W_cheb + 4096; break;                  // W1
      case 6: s = W_cheb + 8192; break;                  // W2
      case 7: s = W_gcn; break;
      default: s = W_gat; break;
    }
    for (int ee = threadIdx.x; ee < 4096; ee += 256){
      int k = ee >> 6, n = ee & 63;
      float f = s[ee];
      if (sub) f -= sub[ee];
      wpk[(size_t)w*4096 + (size_t)n*64 + k] = f2bf(f);
    }
  } else if (b < 3136){
    int i = (b - 10)*256 + threadIdx.x;
    if (i < NN*16){
      float4 v = x4[i];
      ushort4 o;
      o.x = f2bf(v.x); o.y = f2bf(v.y); o.z = f2bf(v.z); o.w = f2bf(v.w);
      xb4[i] = o;
    } else if (i < (NN+1)*16){
      ushort4 z; z.x = 0; z.y = 0; z.z = 0; z.w = 0;
      xb4[i] = z;
      t1b4[i] = z;            // t1b zero row at same row index NN
    }
  }
}

// ---------------- per-node scalars: {dinvc, dinv, el, er} ----------------
__global__ __launch_bounds__(256) void k_nodal(const float* __restrict__ x,
    const int* __restrict__ cnt, const float* __restrict__ va, const float* __restrict__ vb,
    float4* __restrict__ nodal){
  int tid = threadIdx.x;
  int li = tid & 15;
  int row = blockIdx.x*16 + (tid >> 4);
  if (row >= NN) return;
  float4 hv = *(const float4*)&x[(size_t)row*64 + li*4];
  float4 av = *(const float4*)&va[li*4];
  float4 bv = *(const float4*)&vb[li*4];
  float ps = hv.x*av.x + hv.y*av.y + hv.z*av.z + hv.w*av.w;
  float pd = hv.x*bv.x + hv.y*bv.y + hv.z*bv.z + hv.w*bv.w;
  #pragma unroll
  for (int o = 1; o < 16; o <<= 1){ ps += __shfl_xor(ps, o); pd += __shfl_xor(pd, o); }
  if (li == 0){
    float c = (float)cnt[row];
    float dinv  = rsqrtf(c + 1.f);
    float dinvc = rsqrtf(fmaxf(c, 1.f));
    nodal[row] = make_float4(dinvc, dinv, ps, pd);
  }
}

// ---------------- pass A: 2 nodes/wave (one per 32-lane half) -> nsb,t1b,v1b,gb ------
// Each half stages its OWN node's <=32 edges (staging serves 2 nodes per pass);
// lane covers dims 2hl,2hl+1 via one dword gather; no cross-half combine needed.
__global__ __launch_bounds__(256) void k_aggA(const float* __restrict__ x,
    const unsigned short* __restrict__ xb,
    const int* __restrict__ cnt, const unsigned short* __restrict__ slot,
    const float4* __restrict__ nodal,
    unsigned* __restrict__ nsb2, unsigned* __restrict__ t1b2,
    unsigned* __restrict__ v1b2, unsigned* __restrict__ gb2){
  __shared__ float4 sW[4][64];
  int wid  = threadIdx.x >> 6;
  int lane = threadIdx.x & 63;
  int half = lane >> 5, hl = lane & 31;
  int node = blockIdx.x*8 + wid*2 + half;     // grid 6250 -> nodes 0..49999 exactly
  int c = min(cnt[node], CAP);
  int cmax = max(c, __shfl_xor(c, 32));       // wave-uniform loop bound
  const unsigned short* sl = slot + (size_t)node*CAP;
  float4 nn = nodal[node];                    // {dinvc, dinv, el, er}
  float ern = nn.w;
  float a0e=0.f,a0o=0.f,a1e=0.f,a1o=0.f,a2e=0.f,a2o=0.f,a3e=0.f,a3o=0.f, zl=0.f;
  for (int base = 0; base < cmax; base += 32){
    int rem = c - base;                       // this half's remaining (may be <=0)
    bool act = hl < rem;
    int s = act ? (int)sl[base+hl] : NN;      // NN = zero row
    float4 ns = act ? nodal[s] : make_float4(0.f,0.f,0.f,0.f);
    float p = act ? __expf(fminf(leaky02(ns.z + ern), 60.f)) : 0.f;
    zl += p;
    sW[wid][lane] = make_float4(__int_as_float(s), ns.x, ns.y, p);
    lds_fence();                   // wave-sync: ds_write visible before broadcast reads
    int remw = min(32, cmax - base);
    for (int j = 0; j < remw; j += 4){        // 4 edges per half per iter
      float4 w[4]; unsigned uv[4];
      #pragma unroll
      for (int q2 = 0; q2 < 4; ++q2){
        w[q2] = sW[wid][half*32 + j + q2];    // 2 distinct addrs per wave: free 2-way
        int sb = __float_as_int(w[q2].x);
        sb = ((unsigned)sb <= (unsigned)NN) ? sb : NN;   // defensive clamp
        uv[q2] = *(const unsigned*)&xb[(size_t)sb*64 + 2*hl];
      }
      #pragma unroll
      for (int q2 = 0; q2 < 4; ++q2){
        float lo = __uint_as_float(uv[q2] << 16);
        float hi = __uint_as_float(uv[q2] & 0xffff0000u);
        a0e += lo;                       a0o += hi;
        a1e = fmaf(w[q2].y, lo, a1e);    a1o = fmaf(w[q2].y, hi, a1o);
        a2e = fmaf(w[q2].z, lo, a2e);    a2o = fmaf(w[q2].z, hi, a2o);
        a3e = fmaf(w[q2].w, lo, a3e);    a3o = fmaf(w[q2].w, hi, a3o);
      }
    }
    lds_fence();                   // reads done before next chunk overwrites sW
  }
  #pragma unroll
  for (int o = 1; o <= 16; o <<= 1) zl += __shfl_xor(zl, o);   // within-half reduce
  float2 xs = *(const float2*)&x[(size_t)node*64 + 2*hl];      // self terms exact (fp32)
  float p_self = __expf(fminf(leaky02(nn.z + nn.w), 60.f));
  float rz = 1.f / (zl + p_self + 1e-16f);
  size_t off2 = (size_t)node*32 + hl;        // node,node+1 adjacent: 64-lane contiguous
  nsb2[off2] = pack2(f2bf(a0e), f2bf(a0o));
  t1b2[off2] = pack2(f2bf(-nn.x*a1e), f2bf(-nn.x*a1o));
  v1b2[off2] = pack2(f2bf(nn.y*a2e + nn.y*nn.y*xs.x), f2bf(nn.y*a2o + nn.y*nn.y*xs.y));
  gb2[off2]  = pack2(f2bf((a3e + p_self*xs.x)*rz), f2bf((a3o + p_self*xs.y)*rz));
}

// ---------------- pass B: 2 nodes/wave gather of t1b -> ub ----------------
__global__ __launch_bounds__(256) void k_aggB(const unsigned short* __restrict__ t1b,
    const int* __restrict__ cnt, const unsigned short* __restrict__ slot,
    const float4* __restrict__ nodal, unsigned* __restrict__ ub2){
  __shared__ float2 sW[4][64];
  int wid  = threadIdx.x >> 6;
  int lane = threadIdx.x & 63;
  int half = lane >> 5, hl = lane & 31;
  int node = blockIdx.x*8 + wid*2 + half;
  int c = min(cnt[node], CAP);
  int cmax = max(c, __shfl_xor(c, 32));
  const unsigned short* sl = slot + (size_t)node*CAP;
  const float* nf = (const float*)nodal;
  float ae = 0.f, ao = 0.f;
  for (int base = 0; base < cmax; base += 32){
    int rem = c - base;
    bool act = hl < rem;
    int s = act ? (int)sl[base+hl] : NN;      // NN = zero row
    float dc = act ? nf[(size_t)s*4] : 0.f;
    sW[wid][lane] = make_float2(__int_as_float(s), dc);
    lds_fence();
    int remw = min(32, cmax - base);
    for (int j = 0; j < remw; j += 4){
      float2 w[4]; unsigned uv[4];
      #pragma unroll
      for (int q2 = 0; q2 < 4; ++q2){
        w[q2] = sW[wid][half*32 + j + q2];
        int sb = __float_as_int(w[q2].x);
        sb = ((unsigned)sb <= (unsigned)NN) ? sb : NN;
        uv[q2] = *(const unsigned*)&t1b[(size_t)sb*64 + 2*hl];
      }
      #pragma unroll
      for (int q2 = 0; q2 < 4; ++q2){
        float lo = __uint_as_float(uv[q2] << 16);
        float hi = __uint_as_float(uv[q2] & 0xffff0000u);
        ae = fmaf(w[q2].y, lo, ae);
        ao = fmaf(w[q2].y, hi, ao);
      }
    }
    lds_fence();
  }
  float sc = -2.f * nodal[node].x;
  ub2[(size_t)node*32 + hl] = pack2(f2bf(sc*ae), f2bf(sc*ao));
}

// ---------------- epilogue: barrier-free, LDS-free bf16 MFMA, 1 wave/block --------
__global__ __launch_bounds__(64) void k_epi(
    const float* __restrict__ wts,
    const float* __restrict__ b_mlp, const float* __restrict__ b_sage,
    const float* __restrict__ b_gcn, const float* __restrict__ b_gat,
    const float* __restrict__ b_cheb, const float* __restrict__ b_gin,
    const float4* __restrict__ nodal, const unsigned short* __restrict__ wpk,
    const unsigned short* __restrict__ xb, const unsigned short* __restrict__ nsb,
    const unsigned short* __restrict__ t1b, const unsigned short* __restrict__ v1b,
    const unsigned short* __restrict__ gb, const unsigned short* __restrict__ ub,
    float* __restrict__ out){
  const int lane = threadIdx.x;
  const int ml   = lane & 15;          // MFMA m / n / col index
  const int q    = lane >> 4;          // quad
  const int rowbase = blockIdx.x*16;
  const float w0 = wts[0], w1 = wts[1], w2 = wts[2], w3 = wts[3], w4 = wts[4], w5 = wts[5];
  const float* nod = (const float*)nodal;

  short8 ah0, ah1;

  auto loadA = [&](const unsigned short* __restrict__ src){
    const unsigned short* p = src + (size_t)(rowbase + ml)*64 + q*8;
    ah0 = *(const short8*)p;
    ah1 = *(const short8*)(p + 32);
  };
  auto group = [&](int w, f32x4 acc[4]){
    const unsigned short* base = wpk + (size_t)w*4096;
    #pragma unroll
    for (int nt = 0; nt < 4; ++nt){
      const unsigned short* bp = base + (size_t)(nt*16 + ml)*64;
      short8 b0 = *(const short8*)(bp + q*8);
      short8 b1 = *(const short8*)(bp + 32 + q*8);
      acc[nt] = __builtin_amdgcn_mfma_f32_16x16x32_bf16(ah0, b0, acc[nt], 0, 0, 0);
      acc[nt] = __builtin_amdgcn_mfma_f32_16x16x32_bf16(ah1, b1, acc[nt], 0, 0, 0);
    }
  };

  f32x4 res[4];
  #pragma unroll
  for (int i = 0; i < 4; ++i) res[i] = (f32x4){0.f,0.f,0.f,0.f};

  auto emit = [&](const f32x4 acc[4], const float* __restrict__ bias, float wk){
    #pragma unroll
    for (int nt = 0; nt < 4; ++nt){
      float b = bias[nt*16 + ml];
      #pragma unroll
      for (int r = 0; r < 4; ++r) res[nt][r] += wk * eluf(acc[nt][r] + b);
    }
  };

  f32x4 t[4], accC[4], accWr[4], accG[4];

  // gcn
  loadA(v1b);
  #pragma unroll
  for (int i=0;i<4;++i) t[i] = (f32x4){0.f,0.f,0.f,0.f};
  group(7, t); emit(t, b_gcn, w2);
  // gat
  loadA(gb);
  #pragma unroll
  for (int i=0;i<4;++i) t[i] = (f32x4){0.f,0.f,0.f,0.f};
  group(8, t); emit(t, b_gat, w3);
  // cheb partials: u@W2, T1@W1
  loadA(ub);
  #pragma unroll
  for (int i=0;i<4;++i) accC[i] = (f32x4){0.f,0.f,0.f,0.f};
  group(6, accC);
  loadA(t1b);
  group(5, accC);
  // A = x: mlp, Wr, W0-W2 (finish cheb), gin-start
  loadA(xb);
  #pragma unroll
  for (int i=0;i<4;++i) t[i] = (f32x4){0.f,0.f,0.f,0.f};
  group(0, t); emit(t, b_mlp, w0);
  #pragma unroll
  for (int i=0;i<4;++i) accWr[i] = (f32x4){0.f,0.f,0.f,0.f};
  group(1, accWr);
  group(2, accC); emit(accC, b_cheb, w4);
  #pragma unroll
  for (int i=0;i<4;++i) accG[i] = (f32x4){0.f,0.f,0.f,0.f};
  group(3, accG);
  // A = nsum: finish gin, then sage
  loadA(nsb);
  group(3, accG); emit(accG, b_gin, w5);
  #pragma unroll
  for (int i=0;i<4;++i) t[i] = (f32x4){0.f,0.f,0.f,0.f};
  group(4, t);
  #pragma unroll
  for (int nt = 0; nt < 4; ++nt){
    float b = b_sage[nt*16 + ml];
    #pragma unroll
    for (int r = 0; r < 4; ++r){
      int row = rowbase + q*4 + r;
      float dc = nod[(size_t)row*4];     // dinvc
      float invd = dc*dc;                // 1/max(deg,1)
      res[nt][r] += w1 * eluf(invd*t[nt][r] + accWr[nt][r] + b);
    }
  }
  // store (C/D layout: col=lane&15, row=q*4+r)
  #pragma unroll
  for (int nt = 0; nt < 4; ++nt){
    int col = nt*16 + ml;
    #pragma unroll
    for (int r = 0; r < 4; ++r){
      int row = rowbase + q*4 + r;
      out[(size_t)row*64 + col] = res[nt][r];
    }
  }
}

extern "C" void kernel_launch(void* const* d_in, const int* in_sizes, int n_in,
                              void* d_out, int out_size, void* d_ws, size_t ws_size,
                              hipStream_t stream){
  const float* x      = (const float*)d_in[0];
  const float* wts    = (const float*)d_in[1];
  const float* W_mlp  = (const float*)d_in[2];
  const float* b_mlp  = (const float*)d_in[3];
  const float* Wl     = (const float*)d_in[4];
  const float* Wr     = (const float*)d_in[5];
  const float* b_sage = (const float*)d_in[6];
  const float* W_gcn  = (const float*)d_in[7];
  const float* b_gcn  = (const float*)d_in[8];
  const float* W_gat  = (const float*)d_in[9];
  const float* a_src  = (const float*)d_in[10];
  const float* a_dst  = (const float*)d_in[11];
  const float* b_gat  = (const float*)d_in[12];
  const float* W_cheb = (const float*)d_in[13];
  const float* b_cheb = (const float*)d_in[14];
  const float* W_gin  = (const float*)d_in[15];
  const float* b_gin  = (const float*)d_in[16];
  const int*   ei     = (const int*)d_in[17];

  float* wsf  = (float*)d_ws;
  int*  cnt   = (int*)d_ws;
  unsigned short* slot = (unsigned short*)(wsf + O_SLOT);
  float4* nodal = (float4*)(wsf + O_NODAL);
  float* va   = wsf + O_VA;
  float* vb   = wsf + O_VB;
  unsigned short* xbu = (unsigned short*)(wsf + O_XB);
  unsigned short* nsb = (unsigned short*)(wsf + O_NSB);
  unsigned short* t1b = (unsigned short*)(wsf + O_T1B);
  unsigned short* v1b = (unsigned short*)(wsf + O_V1B);
  unsigned short* gb  = (unsigned short*)(wsf + O_GB);
  unsigned short* ub  = (unsigned short*)(wsf + O_UB);
  unsigned short* wpk = (unsigned short*)(wsf + O_WPK);
  float* out  = (float*)d_out;

  hipMemsetAsync(cnt, 0, NN*sizeof(int), stream);
  k_scatter <<<25000,256, 0, stream>>>(ei, ei + NE, cnt, slot,
                                       W_mlp, Wr, W_cheb, W_gin, Wl, W_gcn, W_gat,
                                       a_src, a_dst, (const float4*)x,
                                       va, vb, wpk, (ushort4*)xbu, (ushort4*)t1b);
  k_nodal   <<<3125, 256, 0, stream>>>(x, cnt, va, vb, nodal);
  k_aggA    <<<6250, 256, 0, stream>>>(x, xbu, cnt, slot, nodal,
                                       (unsigned*)nsb, (unsigned*)t1b,
                                       (unsigned*)v1b, (unsigned*)gb);
  k_aggB    <<<6250, 256, 0, stream>>>(t1b, cnt, slot, nodal, (unsigned*)ub);
  k_epi     <<<3125,  64, 0, stream>>>(wts, b_mlp, b_sage, b_gcn, b_gat, b_cheb, b_gin,
                                       nodal, wpk, xbu, nsb, t1b, v1b, gb, ub, out);
}

// Round 13
// 217.162 us; speedup vs baseline: 1.0715x; 1.0110x over previous
//
#include <hip/hip_runtime.h>
#include <cstdint>
#include <cstddef>

#define NN 50000
#define NE 800000
#define CAP 96      // max in-degree bucket (Poisson(16): P(deg>=96) ~ 1e-42)
#define NSEG 8      // dst-range segments (XCD-aligned via blockIdx&7)
#define SEGW 6250   // NN / NSEG

// ---------------- ws layout (units of 4 bytes) ----------------
constexpr size_t O_CNT   = 0;                        // int[NN]
constexpr size_t O_SLOT  = 50048;                    // ushort[NN*CAP] (region kept int-sized)
constexpr size_t O_NODAL = O_SLOT + (size_t)NN*CAP;  // float4[NN] {dinvc,dinv,el,er}
constexpr size_t O_VA    = O_NODAL + 200000;         // 64
constexpr size_t O_VB    = O_VA + 64;                // 64
constexpr size_t O_XB    = O_VB + 64;                // ushort[(NN+1)*64] bf16 x (+zero row)
constexpr size_t O_NSB   = O_XB + 1600032;           // ushort[NN*64] bf16 nsum
constexpr size_t O_T1B   = O_NSB + 1600000;          // ushort[(NN+1)*64] bf16 T1 (+zero row)
constexpr size_t O_V1B   = O_T1B + 1600032;          // ushort[NN*64]
constexpr size_t O_GB    = O_V1B + 1600000;          // ushort[NN*64]
constexpr size_t O_UB    = O_GB  + 1600000;          // ushort[NN*64]
constexpr size_t O_WPK   = O_UB  + 1600000;          // ushort[9*4096] bf16 weights
// total ~59 MB

typedef __attribute__((ext_vector_type(8))) short short8;   // 8 bf16 (4 VGPRs)
typedef __attribute__((ext_vector_type(4))) float f32x4;

__device__ __forceinline__ float leaky02(float v){ return v >= 0.f ? v : 0.2f*v; }
__device__ __forceinline__ float eluf(float v){ return v > 0.f ? v : (__expf(v) - 1.f); }

// intra-wave LDS producer->consumer fence (wave-synchronous pattern)
__device__ __forceinline__ void lds_fence(){
  asm volatile("s_waitcnt lgkmcnt(0)" ::: "memory");
}

__device__ __forceinline__ unsigned short f2bf(float f){   // round-to-nearest-even
  unsigned u = __float_as_uint(f);
  unsigned r = (u + 0x7FFFu + ((u >> 16) & 1u)) >> 16;
  return (unsigned short)r;
}
__device__ __forceinline__ float bf2f(unsigned short b){
  return __uint_as_float(((unsigned)b) << 16);
}
__device__ __forceinline__ unsigned pack2(unsigned short lo, unsigned short hi){
  return (unsigned)lo | ((unsigned)hi << 16);
}

// ---------------- fused: XCD-segmented bucket build + prep (va/wpk/xcast) ----------
__global__ __launch_bounds__(256) void k_scatter(
    const int* __restrict__ src, const int* __restrict__ dst,
    int* __restrict__ cnt, unsigned short* __restrict__ slot,
    const float* __restrict__ W_mlp, const float* __restrict__ Wr,
    const float* __restrict__ W_cheb, const float* __restrict__ W_gin,
    const float* __restrict__ Wl, const float* __restrict__ W_gcn,
    const float* __restrict__ W_gat,
    const float* __restrict__ a_src, const float* __restrict__ a_dst,
    const float4* __restrict__ x4,
    float* __restrict__ va, float* __restrict__ vb,
    unsigned short* __restrict__ wpk,
    ushort4* __restrict__ xb4, ushort4* __restrict__ t1b4){
  int b = blockIdx.x;
  int seg = b & (NSEG-1);
  int lo = seg * SEGW;
  int e = (b >> 3)*256 + threadIdx.x;
  if (e < NE){
    int d = dst[e];
    if ((unsigned)(d - lo) < (unsigned)SEGW){   // single unsigned range compare
      int s = src[e];
      int pos = atomicAdd(&cnt[d], 1);
      if (pos < CAP) slot[(size_t)d*CAP + pos] = (unsigned short)s;
    }
  }
  // ---- fused prep ----
  if (b == 0){
    int k = threadIdx.x;
    if (k < 64){
      float sa = 0.f, sb = 0.f;
      for (int j = 0; j < 64; ++j){
        float w = W_gat[k*64 + j];
        sa = fmaf(w, a_src[j], sa);
        sb = fmaf(w, a_dst[j], sb);
      }
      va[k] = sa; vb[k] = sb;
    }
  } else if (b <= 9){
    int w = b - 1;
    const float* s; const float* sub = nullptr;
    switch (w){
      case 0: s = W_mlp; break;
      case 1: s = Wr; break;
      case 2: s = W_cheb; sub = W_cheb + 8192; break;   // W0 - W2
      case 3: s = W_gin; break;
      case 4: s = Wl; break;
      case 5: s = W_cheb + 4096; break;                  // W1
      case 6: s = W_cheb + 8192; break;                  // W2
      case 7: s = W_gcn; break;
      default: s = W_gat; break;
    }
    for (int ee = threadIdx.x; ee < 4096; ee += 256){
      int k = ee >> 6, n = ee & 63;
      float f = s[ee];
      if (sub) f -= sub[ee];
      wpk[(size_t)w*4096 + (size_t)n*64 + k] = f2bf(f);
    }
  } else if (b < 3136){
    int i = (b - 10)*256 + threadIdx.x;
    if (i < NN*16){
      float4 v = x4[i];
      ushort4 o;
      o.x = f2bf(v.x); o.y = f2bf(v.y); o.z = f2bf(v.z); o.w = f2bf(v.w);
      xb4[i] = o;
    } else if (i < (NN+1)*16){
      ushort4 z; z.x = 0; z.y = 0; z.z = 0; z.w = 0;
      xb4[i] = z;
      t1b4[i] = z;            // t1b zero row at same row index NN
    }
  }
}

// ---------------- per-node scalars: {dinvc, dinv, el, er} (bf16 x reads) ----------
__global__ __launch_bounds__(256) void k_nodal(const unsigned short* __restrict__ xb,
    const int* __restrict__ cnt, const float* __restrict__ va, const float* __restrict__ vb,
    float4* __restrict__ nodal){
  int tid = threadIdx.x;
  int li = tid & 15;
  int row = blockIdx.x*16 + (tid >> 4);
  if (row >= NN) return;
  ushort4 hb = *(const ushort4*)&xb[(size_t)row*64 + li*4];
  float4 hv = make_float4(bf2f(hb.x), bf2f(hb.y), bf2f(hb.z), bf2f(hb.w));
  float4 av = *(const float4*)&va[li*4];
  float4 bv = *(const float4*)&vb[li*4];
  float ps = hv.x*av.x + hv.y*av.y + hv.z*av.z + hv.w*av.w;
  float pd = hv.x*bv.x + hv.y*bv.y + hv.z*bv.z + hv.w*bv.w;
  #pragma unroll
  for (int o = 1; o < 16; o <<= 1){ ps += __shfl_xor(ps, o); pd += __shfl_xor(pd, o); }
  if (li == 0){
    float c = (float)cnt[row];
    float dinv  = rsqrtf(c + 1.f);
    float dinvc = rsqrtf(fmaxf(c, 1.f));
    nodal[row] = make_float4(dinvc, dinv, ps, pd);
  }
}

// ---------------- pass A: 2 nodes/wave (one per 32-lane half) -> nsb,t1b,v1b,gb ------
__global__ __launch_bounds__(256) void k_aggA(
    const unsigned short* __restrict__ xb,
    const int* __restrict__ cnt, const unsigned short* __restrict__ slot,
    const float4* __restrict__ nodal,
    unsigned* __restrict__ nsb2, unsigned* __restrict__ t1b2,
    unsigned* __restrict__ v1b2, unsigned* __restrict__ gb2){
  __shared__ float4 sW[4][64];
  int wid  = threadIdx.x >> 6;
  int lane = threadIdx.x & 63;
  int half = lane >> 5, hl = lane & 31;
  int node = blockIdx.x*8 + wid*2 + half;     // grid 6250 -> nodes 0..49999 exactly
  int c = min(cnt[node], CAP);
  int cmax = max(c, __shfl_xor(c, 32));       // wave-uniform loop bound
  const unsigned short* sl = slot + (size_t)node*CAP;
  float4 nn = nodal[node];                    // {dinvc, dinv, el, er}
  float ern = nn.w;
  float a0e=0.f,a0o=0.f,a1e=0.f,a1o=0.f,a2e=0.f,a2o=0.f,a3e=0.f,a3o=0.f, zl=0.f;
  for (int base = 0; base < cmax; base += 32){
    int rem = c - base;                       // this half's remaining (may be <=0)
    bool act = hl < rem;
    int s = act ? (int)sl[base+hl] : NN;      // NN = zero row
    float4 ns = act ? nodal[s] : make_float4(0.f,0.f,0.f,0.f);
    float p = act ? __expf(fminf(leaky02(ns.z + ern), 60.f)) : 0.f;
    zl += p;
    sW[wid][lane] = make_float4(__int_as_float(s), ns.x, ns.y, p);
    lds_fence();                   // wave-sync: ds_write visible before broadcast reads
    int remw = min(32, cmax - base);
    for (int j = 0; j < remw; j += 4){        // 4 edges per half per iter
      float4 w[4]; unsigned uv[4];
      #pragma unroll
      for (int q2 = 0; q2 < 4; ++q2){
        w[q2] = sW[wid][half*32 + j + q2];    // 2 distinct addrs per wave: free 2-way
        int sb = __float_as_int(w[q2].x);
        sb = ((unsigned)sb <= (unsigned)NN) ? sb : NN;   // defensive clamp
        uv[q2] = *(const unsigned*)&xb[(size_t)sb*64 + 2*hl];
      }
      #pragma unroll
      for (int q2 = 0; q2 < 4; ++q2){
        float lo = __uint_as_float(uv[q2] << 16);
        float hi = __uint_as_float(uv[q2] & 0xffff0000u);
        a0e += lo;                       a0o += hi;
        a1e = fmaf(w[q2].y, lo, a1e);    a1o = fmaf(w[q2].y, hi, a1o);
        a2e = fmaf(w[q2].z, lo, a2e);    a2o = fmaf(w[q2].z, hi, a2o);
        a3e = fmaf(w[q2].w, lo, a3e);    a3o = fmaf(w[q2].w, hi, a3o);
      }
    }
    lds_fence();                   // reads done before next chunk overwrites sW
  }
  #pragma unroll
  for (int o = 1; o <= 16; o <<= 1) zl += __shfl_xor(zl, o);   // within-half reduce
  unsigned uxs = *(const unsigned*)&xb[(size_t)node*64 + 2*hl]; // self terms (bf16)
  float xsx = __uint_as_float(uxs << 16);
  float xsy = __uint_as_float(uxs & 0xffff0000u);
  float p_self = __expf(fminf(leaky02(nn.z + nn.w), 60.f));
  float rz = 1.f / (zl + p_self + 1e-16f);
  size_t off2 = (size_t)node*32 + hl;        // node,node+1 adjacent: 64-lane contiguous
  nsb2[off2] = pack2(f2bf(a0e), f2bf(a0o));
  t1b2[off2] = pack2(f2bf(-nn.x*a1e), f2bf(-nn.x*a1o));
  v1b2[off2] = pack2(f2bf(nn.y*a2e + nn.y*nn.y*xsx), f2bf(nn.y*a2o + nn.y*nn.y*xsy));
  gb2[off2]  = pack2(f2bf((a3e + p_self*xsx)*rz), f2bf((a3o + p_self*xsy)*rz));
}

// ---------------- pass B: 2 nodes/wave gather of t1b -> ub ----------------
__global__ __launch_bounds__(256) void k_aggB(const unsigned short* __restrict__ t1b,
    const int* __restrict__ cnt, const unsigned short* __restrict__ slot,
    const float4* __restrict__ nodal, unsigned* __restrict__ ub2){
  __shared__ float2 sW[4][64];
  int wid  = threadIdx.x >> 6;
  int lane = threadIdx.x & 63;
  int half = lane >> 5, hl = lane & 31;
  int node = blockIdx.x*8 + wid*2 + half;
  int c = min(cnt[node], CAP);
  int cmax = max(c, __shfl_xor(c, 32));
  const unsigned short* sl = slot + (size_t)node*CAP;
  const float* nf = (const float*)nodal;
  float ae = 0.f, ao = 0.f;
  for (int base = 0; base < cmax; base += 32){
    int rem = c - base;
    bool act = hl < rem;
    int s = act ? (int)sl[base+hl] : NN;      // NN = zero row
    float dc = act ? nf[(size_t)s*4] : 0.f;
    sW[wid][lane] = make_float2(__int_as_float(s), dc);
    lds_fence();
    int remw = min(32, cmax - base);
    for (int j = 0; j < remw; j += 4){
      float2 w[4]; unsigned uv[4];
      #pragma unroll
      for (int q2 = 0; q2 < 4; ++q2){
        w[q2] = sW[wid][half*32 + j + q2];
        int sb = __float_as_int(w[q2].x);
        sb = ((unsigned)sb <= (unsigned)NN) ? sb : NN;
        uv[q2] = *(const unsigned*)&t1b[(size_t)sb*64 + 2*hl];
      }
      #pragma unroll
      for (int q2 = 0; q2 < 4; ++q2){
        float lo = __uint_as_float(uv[q2] << 16);
        float hi = __uint_as_float(uv[q2] & 0xffff0000u);
        ae = fmaf(w[q2].y, lo, ae);
        ao = fmaf(w[q2].y, hi, ao);
      }
    }
    lds_fence();
  }
  float sc = -2.f * nodal[node].x;
  ub2[(size_t)node*32 + hl] = pack2(f2bf(sc*ae), f2bf(sc*ao));
}

// ---------------- epilogue: barrier-free, LDS-free bf16 MFMA, 1 wave/block --------
__global__ __launch_bounds__(64) void k_epi(
    const float* __restrict__ wts,
    const float* __restrict__ b_mlp, const float* __restrict__ b_sage,
    const float* __restrict__ b_gcn, const float* __restrict__ b_gat,
    const float* __restrict__ b_cheb, const float* __restrict__ b_gin,
    const float4* __restrict__ nodal, const unsigned short* __restrict__ wpk,
    const unsigned short* __restrict__ xb, const unsigned short* __restrict__ nsb,
    const unsigned short* __restrict__ t1b, const unsigned short* __restrict__ v1b,
    const unsigned short* __restrict__ gb, const unsigned short* __restrict__ ub,
    float* __restrict__ out){
  const int lane = threadIdx.x;
  const int ml   = lane & 15;          // MFMA m / n / col index
  const int q    = lane >> 4;          // quad
  const int rowbase = blockIdx.x*16;
  const float w0 = wts[0], w1 = wts[1], w2 = wts[2], w3 = wts[3], w4 = wts[4], w5 = wts[5];
  const float* nod = (const float*)nodal;

  short8 ah0, ah1;

  auto loadA = [&](const unsigned short* __restrict__ src){
    const unsigned short* p = src + (size_t)(rowbase + ml)*64 + q*8;
    ah0 = *(const short8*)p;
    ah1 = *(const short8*)(p + 32);
  };
  auto group = [&](int w, f32x4 acc[4]){
    const unsigned short* base = wpk + (size_t)w*4096;
    #pragma unroll
    for (int nt = 0; nt < 4; ++nt){
      const unsigned short* bp = base + (size_t)(nt*16 + ml)*64;
      short8 b0 = *(const short8*)(bp + q*8);
      short8 b1 = *(const short8*)(bp + 32 + q*8);
      acc[nt] = __builtin_amdgcn_mfma_f32_16x16x32_bf16(ah0, b0, acc[nt], 0, 0, 0);
      acc[nt] = __builtin_amdgcn_mfma_f32_16x16x32_bf16(ah1, b1, acc[nt], 0, 0, 0);
    }
  };

  f32x4 res[4];
  #pragma unroll
  for (int i = 0; i < 4; ++i) res[i] = (f32x4){0.f,0.f,0.f,0.f};

  auto emit = [&](const f32x4 acc[4], const float* __restrict__ bias, float wk){
    #pragma unroll
    for (int nt = 0; nt < 4; ++nt){
      float b = bias[nt*16 + ml];
      #pragma unroll
      for (int r = 0; r < 4; ++r) res[nt][r] += wk * eluf(acc[nt][r] + b);
    }
  };

  f32x4 t[4], accC[4], accWr[4], accG[4];

  // gcn
  loadA(v1b);
  #pragma unroll
  for (int i=0;i<4;++i) t[i] = (f32x4){0.f,0.f,0.f,0.f};
  group(7, t); emit(t, b_gcn, w2);
  // gat
  loadA(gb);
  #pragma unroll
  for (int i=0;i<4;++i) t[i] = (f32x4){0.f,0.f,0.f,0.f};
  group(8, t); emit(t, b_gat, w3);
  // cheb partials: u@W2, T1@W1
  loadA(ub);
  #pragma unroll
  for (int i=0;i<4;++i) accC[i] = (f32x4){0.f,0.f,0.f,0.f};
  group(6, accC);
  loadA(t1b);
  group(5, accC);
  // A = x: mlp, Wr, W0-W2 (finish cheb), gin-start
  loadA(xb);
  #pragma unroll
  for (int i=0;i<4;++i) t[i] = (f32x4){0.f,0.f,0.f,0.f};
  group(0, t); emit(t, b_mlp, w0);
  #pragma unroll
  for (int i=0;i<4;++i) accWr[i] = (f32x4){0.f,0.f,0.f,0.f};
  group(1, accWr);
  group(2, accC); emit(accC, b_cheb, w4);
  #pragma unroll
  for (int i=0;i<4;++i) accG[i] = (f32x4){0.f,0.f,0.f,0.f};
  group(3, accG);
  // A = nsum: finish gin, then sage
  loadA(nsb);
  group(3, accG); emit(accG, b_gin, w5);
  #pragma unroll
  for (int i=0;i<4;++i) t[i] = (f32x4){0.f,0.f,0.f,0.f};
  group(4, t);
  #pragma unroll
  for (int nt = 0; nt < 4; ++nt){
    float b = b_sage[nt*16 + ml];
    #pragma unroll
    for (int r = 0; r < 4; ++r){
      int row = rowbase + q*4 + r;
      float dc = nod[(size_t)row*4];     // dinvc
      float invd = dc*dc;                // 1/max(deg,1)
      res[nt][r] += w1 * eluf(invd*t[nt][r] + accWr[nt][r] + b);
    }
  }
  // store (C/D layout: col=lane&15, row=q*4+r)
  #pragma unroll
  for (int nt = 0; nt < 4; ++nt){
    int col = nt*16 + ml;
    #pragma unroll
    for (int r = 0; r < 4; ++r){
      int row = rowbase + q*4 + r;
      out[(size_t)row*64 + col] = res[nt][r];
    }
  }
}

extern "C" void kernel_launch(void* const* d_in, const int* in_sizes, int n_in,
                              void* d_out, int out_size, void* d_ws, size_t ws_size,
                              hipStream_t stream){
  const float* x      = (const float*)d_in[0];
  const float* wts    = (const float*)d_in[1];
  const float* W_mlp  = (const float*)d_in[2];
  const float* b_mlp  = (const float*)d_in[3];
  const float* Wl     = (const float*)d_in[4];
  const float* Wr     = (const float*)d_in[5];
  const float* b_sage = (const float*)d_in[6];
  const float* W_gcn  = (const float*)d_in[7];
  const float* b_gcn  = (const float*)d_in[8];
  const float* W_gat  = (const float*)d_in[9];
  const float* a_src  = (const float*)d_in[10];
  const float* a_dst  = (const float*)d_in[11];
  const float* b_gat  = (const float*)d_in[12];
  const float* W_cheb = (const float*)d_in[13];
  const float* b_cheb = (const float*)d_in[14];
  const float* W_gin  = (const float*)d_in[15];
  const float* b_gin  = (const float*)d_in[16];
  const int*   ei     = (const int*)d_in[17];

  float* wsf  = (float*)d_ws;
  int*  cnt   = (int*)d_ws;
  unsigned short* slot = (unsigned short*)(wsf + O_SLOT);
  float4* nodal = (float4*)(wsf + O_NODAL);
  float* va   = wsf + O_VA;
  float* vb   = wsf + O_VB;
  unsigned short* xbu = (unsigned short*)(wsf + O_XB);
  unsigned short* nsb = (unsigned short*)(wsf + O_NSB);
  unsigned short* t1b = (unsigned short*)(wsf + O_T1B);
  unsigned short* v1b = (unsigned short*)(wsf + O_V1B);
  unsigned short* gb  = (unsigned short*)(wsf + O_GB);
  unsigned short* ub  = (unsigned short*)(wsf + O_UB);
  unsigned short* wpk = (unsigned short*)(wsf + O_WPK);
  float* out  = (float*)d_out;

  hipMemsetAsync(cnt, 0, NN*sizeof(int), stream);
  k_scatter <<<25000,256, 0, stream>>>(ei, ei + NE, cnt, slot,
                                       W_mlp, Wr, W_cheb, W_gin, Wl, W_gcn, W_gat,
                                       a_src, a_dst, (const float4*)x,
                                       va, vb, wpk, (ushort4*)xbu, (ushort4*)t1b);
  k_nodal   <<<3125, 256, 0, stream>>>(xbu, cnt, va, vb, nodal);
  k_aggA    <<<6250, 256, 0, stream>>>(xbu, cnt, slot, nodal,
                                       (unsigned*)nsb, (unsigned*)t1b,
                                       (unsigned*)v1b, (unsigned*)gb);
  k_aggB    <<<6250, 256, 0, stream>>>(t1b, cnt, slot, nodal, (unsigned*)ub);
  k_epi     <<<3125,  64, 0, stream>>>(wts, b_mlp, b_sage, b_gcn, b_gat, b_cheb, b_gin,
                                       nodal, wpk, xbu, nsb, t1b, v1b, gb, ub, out);
}

// Round 14
// 214.167 us; speedup vs baseline: 1.0865x; 1.0140x over previous
//
#include <hip/hip_runtime.h>
#include <cstdint>
#include <cstddef>

#define NN 50000
#define NE 800000
#define CAP 96      // max in-degree bucket (Poisson(16): P(deg>=96) ~ 1e-42)
#define NSEG 8      // dst-range segments (XCD-aligned via blockIdx&7)
#define SEGW 6250   // NN / NSEG

// ---------------- ws layout (units of 4 bytes) ----------------
constexpr size_t O_CNT   = 0;                        // int[NN]
constexpr size_t O_SLOT  = 50048;                    // ushort[NN*CAP] (region kept int-sized)
constexpr size_t O_NODAL = O_SLOT + (size_t)NN*CAP;  // float4[NN] {dinvc,dinv,el,er}
constexpr size_t O_VA    = O_NODAL + 200000;         // 64
constexpr size_t O_VB    = O_VA + 64;                // 64
constexpr size_t O_XB    = O_VB + 64;                // ushort[(NN+1)*64] bf16 x (+zero row)
constexpr size_t O_NSB   = O_XB + 1600032;           // ushort[NN*64] bf16 nsum
constexpr size_t O_T1B   = O_NSB + 1600000;          // ushort[(NN+1)*64] bf16 T1 (+zero row)
constexpr size_t O_V1B   = O_T1B + 1600032;          // ushort[NN*64]
constexpr size_t O_GB    = O_V1B + 1600000;          // ushort[NN*64]
constexpr size_t O_UB    = O_GB  + 1600000;          // ushort[NN*64]
constexpr size_t O_WPK   = O_UB  + 1600000;          // ushort[9*4096] bf16 weights
// total ~59 MB

typedef __attribute__((ext_vector_type(8))) short short8;   // 8 bf16 (4 VGPRs)
typedef __attribute__((ext_vector_type(4))) float f32x4;

__device__ __forceinline__ float leaky02(float v){ return v >= 0.f ? v : 0.2f*v; }
__device__ __forceinline__ float eluf(float v){ return v > 0.f ? v : (__expf(v) - 1.f); }

// intra-wave LDS producer->consumer fence (wave-synchronous pattern)
__device__ __forceinline__ void lds_fence(){
  asm volatile("s_waitcnt lgkmcnt(0)" ::: "memory");
}

__device__ __forceinline__ unsigned short f2bf(float f){   // round-to-nearest-even
  unsigned u = __float_as_uint(f);
  unsigned r = (u + 0x7FFFu + ((u >> 16) & 1u)) >> 16;
  return (unsigned short)r;
}
__device__ __forceinline__ float bf2f(unsigned short b){
  return __uint_as_float(((unsigned)b) << 16);
}
__device__ __forceinline__ unsigned pack2(unsigned short lo, unsigned short hi){
  return (unsigned)lo | ((unsigned)hi << 16);
}

// ---------------- fused: XCD-segmented bucket build + prep (va/wpk/xcast) ----------
__global__ __launch_bounds__(256) void k_scatter(
    const int* __restrict__ src, const int* __restrict__ dst,
    int* __restrict__ cnt, unsigned short* __restrict__ slot,
    const float* __restrict__ W_mlp, const float* __restrict__ Wr,
    const float* __restrict__ W_cheb, const float* __restrict__ W_gin,
    const float* __restrict__ Wl, const float* __restrict__ W_gcn,
    const float* __restrict__ W_gat,
    const float* __restrict__ a_src, const float* __restrict__ a_dst,
    const float4* __restrict__ x4,
    float* __restrict__ va, float* __restrict__ vb,
    unsigned short* __restrict__ wpk,
    ushort4* __restrict__ xb4, ushort4* __restrict__ t1b4){
  int b = blockIdx.x;
  int seg = b & (NSEG-1);
  int lo = seg * SEGW;
  int e = (b >> 3)*256 + threadIdx.x;
  if (e < NE){
    int d = dst[e];
    if ((unsigned)(d - lo) < (unsigned)SEGW){   // single unsigned range compare
      int s = src[e];
      int pos = atomicAdd(&cnt[d], 1);
      if (pos < CAP) slot[(size_t)d*CAP + pos] = (unsigned short)s;
    }
  }
  // ---- fused prep ----
  if (b == 0){
    int k = threadIdx.x;
    if (k < 64){
      float sa = 0.f, sb = 0.f;
      for (int j = 0; j < 64; ++j){
        float w = W_gat[k*64 + j];
        sa = fmaf(w, a_src[j], sa);
        sb = fmaf(w, a_dst[j], sb);
      }
      va[k] = sa; vb[k] = sb;
    }
  } else if (b <= 9){
    int w = b - 1;
    const float* s; const float* sub = nullptr;
    switch (w){
      case 0: s = W_mlp; break;
      case 1: s = Wr; break;
      case 2: s = W_cheb; sub = W_cheb + 8192; break;   // W0 - W2
      case 3: s = W_gin; break;
      case 4: s = Wl; break;
      case 5: s = W_cheb + 4096; break;                  // W1
      case 6: s = W_cheb + 8192; break;                  // W2
      case 7: s = W_gcn; break;
      default: s = W_gat; break;
    }
    for (int ee = threadIdx.x; ee < 4096; ee += 256){
      int k = ee >> 6, n = ee & 63;
      float f = s[ee];
      if (sub) f -= sub[ee];
      wpk[(size_t)w*4096 + (size_t)n*64 + k] = f2bf(f);
    }
  } else if (b < 3136){
    int i = (b - 10)*256 + threadIdx.x;
    if (i < NN*16){
      float4 v = x4[i];
      ushort4 o;
      o.x = f2bf(v.x); o.y = f2bf(v.y); o.z = f2bf(v.z); o.w = f2bf(v.w);
      xb4[i] = o;
    } else if (i < (NN+1)*16){
      ushort4 z; z.x = 0; z.y = 0; z.z = 0; z.w = 0;
      xb4[i] = z;
      t1b4[i] = z;            // t1b zero row at same row index NN
    }
  }
}

// ---------------- per-node scalars: {dinvc, dinv, el, er} (bf16 x reads) ----------
__global__ __launch_bounds__(256) void k_nodal(const unsigned short* __restrict__ xb,
    const int* __restrict__ cnt, const float* __restrict__ va, const float* __restrict__ vb,
    float4* __restrict__ nodal){
  int tid = threadIdx.x;
  int li = tid & 15;
  int row = blockIdx.x*16 + (tid >> 4);
  if (row >= NN) return;
  ushort4 hb = *(const ushort4*)&xb[(size_t)row*64 + li*4];
  float4 hv = make_float4(bf2f(hb.x), bf2f(hb.y), bf2f(hb.z), bf2f(hb.w));
  float4 av = *(const float4*)&va[li*4];
  float4 bv = *(const float4*)&vb[li*4];
  float ps = hv.x*av.x + hv.y*av.y + hv.z*av.z + hv.w*av.w;
  float pd = hv.x*bv.x + hv.y*bv.y + hv.z*bv.z + hv.w*bv.w;
  #pragma unroll
  for (int o = 1; o < 16; o <<= 1){ ps += __shfl_xor(ps, o); pd += __shfl_xor(pd, o); }
  if (li == 0){
    float c = (float)cnt[row];
    float dinv  = rsqrtf(c + 1.f);
    float dinvc = rsqrtf(fmaxf(c, 1.f));
    nodal[row] = make_float4(dinvc, dinv, ps, pd);
  }
}

// ---------------- pass A: 2 nodes/wave (one per 32-lane half) -> nsb,t1b,v1b,gb ------
// 8 outstanding row-gathers per lane per iter (overrun-safe via zero row).
__global__ __launch_bounds__(256) void k_aggA(
    const unsigned short* __restrict__ xb,
    const int* __restrict__ cnt, const unsigned short* __restrict__ slot,
    const float4* __restrict__ nodal,
    unsigned* __restrict__ nsb2, unsigned* __restrict__ t1b2,
    unsigned* __restrict__ v1b2, unsigned* __restrict__ gb2){
  __shared__ float4 sW[4][64];
  int wid  = threadIdx.x >> 6;
  int lane = threadIdx.x & 63;
  int half = lane >> 5, hl = lane & 31;
  int node = blockIdx.x*8 + wid*2 + half;     // grid 6250 -> nodes 0..49999 exactly
  int c = min(cnt[node], CAP);
  int cmax = max(c, __shfl_xor(c, 32));       // wave-uniform loop bound
  const unsigned short* sl = slot + (size_t)node*CAP;
  float4 nn = nodal[node];                    // {dinvc, dinv, el, er}
  float ern = nn.w;
  float a0e=0.f,a0o=0.f,a1e=0.f,a1o=0.f,a2e=0.f,a2o=0.f,a3e=0.f,a3o=0.f, zl=0.f;
  for (int base = 0; base < cmax; base += 32){
    int rem = c - base;                       // this half's remaining (may be <=0)
    bool act = hl < rem;
    int s = act ? (int)sl[base+hl] : NN;      // NN = zero row
    float4 ns = act ? nodal[s] : make_float4(0.f,0.f,0.f,0.f);
    float p = act ? __expf(fminf(leaky02(ns.z + ern), 60.f)) : 0.f;
    zl += p;
    sW[wid][lane] = make_float4(__int_as_float(s), ns.x, ns.y, p);
    lds_fence();                   // wave-sync: ds_write visible before broadcast reads
    int remw = min(32, cmax - base);
    for (int j = 0; j < remw; j += 8){        // 8 edges per half per iter (8 MLP)
      float4 w[8]; unsigned uv[8];
      #pragma unroll
      for (int q2 = 0; q2 < 8; ++q2){
        w[q2] = sW[wid][half*32 + j + q2];    // 2 distinct addrs per wave: free 2-way
        int sb = __float_as_int(w[q2].x);
        sb = ((unsigned)sb <= (unsigned)NN) ? sb : NN;   // defensive clamp
        uv[q2] = *(const unsigned*)&xb[(size_t)sb*64 + 2*hl];
      }
      #pragma unroll
      for (int q2 = 0; q2 < 8; ++q2){
        float lo = __uint_as_float(uv[q2] << 16);
        float hi = __uint_as_float(uv[q2] & 0xffff0000u);
        a0e += lo;                       a0o += hi;
        a1e = fmaf(w[q2].y, lo, a1e);    a1o = fmaf(w[q2].y, hi, a1o);
        a2e = fmaf(w[q2].z, lo, a2e);    a2o = fmaf(w[q2].z, hi, a2o);
        a3e = fmaf(w[q2].w, lo, a3e);    a3o = fmaf(w[q2].w, hi, a3o);
      }
    }
    lds_fence();                   // reads done before next chunk overwrites sW
  }
  #pragma unroll
  for (int o = 1; o <= 16; o <<= 1) zl += __shfl_xor(zl, o);   // within-half reduce
  unsigned uxs = *(const unsigned*)&xb[(size_t)node*64 + 2*hl]; // self terms (bf16)
  float xsx = __uint_as_float(uxs << 16);
  float xsy = __uint_as_float(uxs & 0xffff0000u);
  float p_self = __expf(fminf(leaky02(nn.z + nn.w), 60.f));
  float rz = 1.f / (zl + p_self + 1e-16f);
  size_t off2 = (size_t)node*32 + hl;        // node,node+1 adjacent: 64-lane contiguous
  nsb2[off2] = pack2(f2bf(a0e), f2bf(a0o));
  t1b2[off2] = pack2(f2bf(-nn.x*a1e), f2bf(-nn.x*a1o));
  v1b2[off2] = pack2(f2bf(nn.y*a2e + nn.y*nn.y*xsx), f2bf(nn.y*a2o + nn.y*nn.y*xsy));
  gb2[off2]  = pack2(f2bf((a3e + p_self*xsx)*rz), f2bf((a3o + p_self*xsy)*rz));
}

// ---------------- pass B: 2 nodes/wave gather of t1b -> ub ----------------
__global__ __launch_bounds__(256) void k_aggB(const unsigned short* __restrict__ t1b,
    const int* __restrict__ cnt, const unsigned short* __restrict__ slot,
    const float4* __restrict__ nodal, unsigned* __restrict__ ub2){
  __shared__ float2 sW[4][64];
  int wid  = threadIdx.x >> 6;
  int lane = threadIdx.x & 63;
  int half = lane >> 5, hl = lane & 31;
  int node = blockIdx.x*8 + wid*2 + half;
  int c = min(cnt[node], CAP);
  int cmax = max(c, __shfl_xor(c, 32));
  const unsigned short* sl = slot + (size_t)node*CAP;
  const float* nf = (const float*)nodal;
  float ae = 0.f, ao = 0.f;
  for (int base = 0; base < cmax; base += 32){
    int rem = c - base;
    bool act = hl < rem;
    int s = act ? (int)sl[base+hl] : NN;      // NN = zero row
    float dc = act ? nf[(size_t)s*4] : 0.f;
    sW[wid][lane] = make_float2(__int_as_float(s), dc);
    lds_fence();
    int remw = min(32, cmax - base);
    for (int j = 0; j < remw; j += 8){        // 8 outstanding gathers per lane
      float2 w[8]; unsigned uv[8];
      #pragma unroll
      for (int q2 = 0; q2 < 8; ++q2){
        w[q2] = sW[wid][half*32 + j + q2];
        int sb = __float_as_int(w[q2].x);
        sb = ((unsigned)sb <= (unsigned)NN) ? sb : NN;
        uv[q2] = *(const unsigned*)&t1b[(size_t)sb*64 + 2*hl];
      }
      #pragma unroll
      for (int q2 = 0; q2 < 8; ++q2){
        float lo = __uint_as_float(uv[q2] << 16);
        float hi = __uint_as_float(uv[q2] & 0xffff0000u);
        ae = fmaf(w[q2].y, lo, ae);
        ao = fmaf(w[q2].y, hi, ao);
      }
    }
    lds_fence();
  }
  float sc = -2.f * nodal[node].x;
  ub2[(size_t)node*32 + hl] = pack2(f2bf(sc*ae), f2bf(sc*ao));
}

// ---------------- epilogue: barrier-free, LDS-free bf16 MFMA, 1 wave/block --------
__global__ __launch_bounds__(64) void k_epi(
    const float* __restrict__ wts,
    const float* __restrict__ b_mlp, const float* __restrict__ b_sage,
    const float* __restrict__ b_gcn, const float* __restrict__ b_gat,
    const float* __restrict__ b_cheb, const float* __restrict__ b_gin,
    const float4* __restrict__ nodal, const unsigned short* __restrict__ wpk,
    const unsigned short* __restrict__ xb, const unsigned short* __restrict__ nsb,
    const unsigned short* __restrict__ t1b, const unsigned short* __restrict__ v1b,
    const unsigned short* __restrict__ gb, const unsigned short* __restrict__ ub,
    float* __restrict__ out){
  const int lane = threadIdx.x;
  const int ml   = lane & 15;          // MFMA m / n / col index
  const int q    = lane >> 4;          // quad
  const int rowbase = blockIdx.x*16;
  const float w0 = wts[0], w1 = wts[1], w2 = wts[2], w3 = wts[3], w4 = wts[4], w5 = wts[5];
  const float* nod = (const float*)nodal;

  short8 ah0, ah1;

  auto loadA = [&](const unsigned short* __restrict__ src){
    const unsigned short* p = src + (size_t)(rowbase + ml)*64 + q*8;
    ah0 = *(const short8*)p;
    ah1 = *(const short8*)(p + 32);
  };
  auto group = [&](int w, f32x4 acc[4]){
    const unsigned short* base = wpk + (size_t)w*4096;
    #pragma unroll
    for (int nt = 0; nt < 4; ++nt){
      const unsigned short* bp = base + (size_t)(nt*16 + ml)*64;
      short8 b0 = *(const short8*)(bp + q*8);
      short8 b1 = *(const short8*)(bp + 32 + q*8);
      acc[nt] = __builtin_amdgcn_mfma_f32_16x16x32_bf16(ah0, b0, acc[nt], 0, 0, 0);
      acc[nt] = __builtin_amdgcn_mfma_f32_16x16x32_bf16(ah1, b1, acc[nt], 0, 0, 0);
    }
  };

  f32x4 res[4];
  #pragma unroll
  for (int i = 0; i < 4; ++i) res[i] = (f32x4){0.f,0.f,0.f,0.f};

  auto emit = [&](const f32x4 acc[4], const float* __restrict__ bias, float wk){
    #pragma unroll
    for (int nt = 0; nt < 4; ++nt){
      float b = bias[nt*16 + ml];
      #pragma unroll
      for (int r = 0; r < 4; ++r) res[nt][r] += wk * eluf(acc[nt][r] + b);
    }
  };

  f32x4 t[4], accC[4], accWr[4], accG[4];

  // gcn
  loadA(v1b);
  #pragma unroll
  for (int i=0;i<4;++i) t[i] = (f32x4){0.f,0.f,0.f,0.f};
  group(7, t); emit(t, b_gcn, w2);
  // gat
  loadA(gb);
  #pragma unroll
  for (int i=0;i<4;++i) t[i] = (f32x4){0.f,0.f,0.f,0.f};
  group(8, t); emit(t, b_gat, w3);
  // cheb partials: u@W2, T1@W1
  loadA(ub);
  #pragma unroll
  for (int i=0;i<4;++i) accC[i] = (f32x4){0.f,0.f,0.f,0.f};
  group(6, accC);
  loadA(t1b);
  group(5, accC);
  // A = x: mlp, Wr, W0-W2 (finish cheb), gin-start
  loadA(xb);
  #pragma unroll
  for (int i=0;i<4;++i) t[i] = (f32x4){0.f,0.f,0.f,0.f};
  group(0, t); emit(t, b_mlp, w0);
  #pragma unroll
  for (int i=0;i<4;++i) accWr[i] = (f32x4){0.f,0.f,0.f,0.f};
  group(1, accWr);
  group(2, accC); emit(accC, b_cheb, w4);
  #pragma unroll
  for (int i=0;i<4;++i) accG[i] = (f32x4){0.f,0.f,0.f,0.f};
  group(3, accG);
  // A = nsum: finish gin, then sage
  loadA(nsb);
  group(3, accG); emit(accG, b_gin, w5);
  #pragma unroll
  for (int i=0;i<4;++i) t[i] = (f32x4){0.f,0.f,0.f,0.f};
  group(4, t);
  #pragma unroll
  for (int nt = 0; nt < 4; ++nt){
    float b = b_sage[nt*16 + ml];
    #pragma unroll
    for (int r = 0; r < 4; ++r){
      int row = rowbase + q*4 + r;
      float dc = nod[(size_t)row*4];     // dinvc
      float invd = dc*dc;                // 1/max(deg,1)
      res[nt][r] += w1 * eluf(invd*t[nt][r] + accWr[nt][r] + b);
    }
  }
  // store (C/D layout: col=lane&15, row=q*4+r)
  #pragma unroll
  for (int nt = 0; nt < 4; ++nt){
    int col = nt*16 + ml;
    #pragma unroll
    for (int r = 0; r < 4; ++r){
      int row = rowbase + q*4 + r;
      out[(size_t)row*64 + col] = res[nt][r];
    }
  }
}

extern "C" void kernel_launch(void* const* d_in, const int* in_sizes, int n_in,
                              void* d_out, int out_size, void* d_ws, size_t ws_size,
                              hipStream_t stream){
  const float* x      = (const float*)d_in[0];
  const float* wts    = (const float*)d_in[1];
  const float* W_mlp  = (const float*)d_in[2];
  const float* b_mlp  = (const float*)d_in[3];
  const float* Wl     = (const float*)d_in[4];
  const float* Wr     = (const float*)d_in[5];
  const float* b_sage = (const float*)d_in[6];
  const float* W_gcn  = (const float*)d_in[7];
  const float* b_gcn  = (const float*)d_in[8];
  const float* W_gat  = (const float*)d_in[9];
  const float* a_src  = (const float*)d_in[10];
  const float* a_dst  = (const float*)d_in[11];
  const float* b_gat  = (const float*)d_in[12];
  const float* W_cheb = (const float*)d_in[13];
  const float* b_cheb = (const float*)d_in[14];
  const float* W_gin  = (const float*)d_in[15];
  const float* b_gin  = (const float*)d_in[16];
  const int*   ei     = (const int*)d_in[17];

  float* wsf  = (float*)d_ws;
  int*  cnt   = (int*)d_ws;
  unsigned short* slot = (unsigned short*)(wsf + O_SLOT);
  float4* nodal = (float4*)(wsf + O_NODAL);
  float* va   = wsf + O_VA;
  float* vb   = wsf + O_VB;
  unsigned short* xbu = (unsigned short*)(wsf + O_XB);
  unsigned short* nsb = (unsigned short*)(wsf + O_NSB);
  unsigned short* t1b = (unsigned short*)(wsf + O_T1B);
  unsigned short* v1b = (unsigned short*)(wsf + O_V1B);
  unsigned short* gb  = (unsigned short*)(wsf + O_GB);
  unsigned short* ub  = (unsigned short*)(wsf + O_UB);
  unsigned short* wpk = (unsigned short*)(wsf + O_WPK);
  float* out  = (float*)d_out;

  hipMemsetAsync(cnt, 0, NN*sizeof(int), stream);
  k_scatter <<<25000,256, 0, stream>>>(ei, ei + NE, cnt, slot,
                                       W_mlp, Wr, W_cheb, W_gin, Wl, W_gcn, W_gat,
                                       a_src, a_dst, (const float4*)x,
                                       va, vb, wpk, (ushort4*)xbu, (ushort4*)t1b);
  k_nodal   <<<3125, 256, 0, stream>>>(xbu, cnt, va, vb, nodal);
  k_aggA    <<<6250, 256, 0, stream>>>(xbu, cnt, slot, nodal,
                                       (unsigned*)nsb, (unsigned*)t1b,
                                       (unsigned*)v1b, (unsigned*)gb);
  k_aggB    <<<6250, 256, 0, stream>>>(t1b, cnt, slot, nodal, (unsigned*)ub);
  k_epi     <<<3125,  64, 0, stream>>>(wts, b_mlp, b_sage, b_gcn, b_gat, b_cheb, b_gin,
                                       nodal, wpk, xbu, nsb, t1b, v1b, gb, ub, out);
}